// Round 7
// baseline (4310.384 us; speedup 1.0000x reference)
//
#include <hip/hip_runtime.h>
#include <math.h>

#define NPTS  32768
#define NB    2
#define NQ    (NB*NPTS)
#define KK    16
#define EPS   1e-6f
#define G     16
#define G3    (G*G*G)
#define HB    2048
#define SLOP  0.05f
#define TEPS  1e-3f
#define CAP   256

// stats / coef element offsets
#define S_L1 0
#define S_L2 32
#define S_P1 64
#define S_P2 96
#define S_SC 160
#define C_L1 0
#define C_L2 32
#define C_P1 64
#define C_P2 96
#define C_SC 160

// workspace element offsets (4-byte units)
#define WS_X1     (NQ*16)
#define WS_T2     (NQ*32)
#define WS_T4     (NQ*48)
#define WS_STAT   (NQ*80)
#define WS_COEF   (WS_STAT + 512)
#define WS_GCNT   (WS_STAT + 1024)
#define WS_GSTART (WS_GCNT + 2*G3)
#define WS_CELLID (WS_GSTART + 2*G3)
#define WS_SORTID (WS_CELLID + NQ)
#define WS_CSORT  (WS_SORTID + NQ)      /* float4 x NQ (16B-aligned) */
#define WS_BBOX   (WS_CSORT + 4*NQ)
#define WS_HIST   (WS_BBOX + 16)
#define WS_EDGE   (WS_HIST + 6*HB)
#define WS_STARTS WS_HIST               /* starts aliases hist (dead after k_edges) */

__device__ __forceinline__ float wred64(float v) {
#pragma unroll
  for (int m = 32; m > 0; m >>= 1) v += __shfl_xor(v, m, 64);
  return v;
}

// order-preserving float <-> uint encoding for atomic min/max
__device__ __forceinline__ unsigned int encf(float f) {
  unsigned int u = __float_as_uint(f);
  return (u & 0x80000000u) ? ~u : (u | 0x80000000u);
}
__device__ __forceinline__ float decf(unsigned int u) {
  return (u & 0x80000000u) ? __uint_as_float(u & 0x7fffffffu) : __uint_as_float(~u);
}

// 4-step binary search over G=16 quantile edges; e[0] <= x guaranteed
__device__ __forceinline__ int bs16(const float* e, float x) {
  int c = (x >= e[8]) ? 8 : 0;
  c += (x >= e[c+4]) ? 4 : 0;
  c += (x >= e[c+2]) ? 2 : 0;
  c += (x >= e[c+1]) ? 1 : 0;
  return c;
}

// 16th-smallest of the 64 lane values (full bitonic sort, value-only)
__device__ __forceinline__ float kth16(float v, int lane) {
#pragma unroll
  for (int k2 = 2; k2 <= 64; k2 <<= 1) {
#pragma unroll
    for (int j = k2 >> 1; j > 0; j >>= 1) {
      float o = __shfl_xor(v, j, 64);
      bool keepmin = (((lane & j) == 0) == ((lane & k2) == 0));
      v = keepmin ? fminf(v, o) : fmaxf(v, o);
    }
  }
  return __shfl(v, 15, 64);
}

// ---------------- zero stats + counters + hist + bbox ----------------
__global__ void k_zero_all(float* __restrict__ stats, int* __restrict__ gcnt,
                           int* __restrict__ hist, unsigned int* __restrict__ bbox) {
  int i = blockIdx.x*256 + threadIdx.x;       // grid covers 12288
  if (i < 2*G3) gcnt[i] = 0;
  if (i < 6*HB) hist[i] = 0;
  if (i < 320)  stats[i] = 0.f;
  if (i < 12)   bbox[i] = ((i % 6) < 3) ? 0xFFFFFFFFu : 0u;
}

// ---------------- per-batch exact bounding box ----------------
__global__ void k_bbox(const float* __restrict__ coords, unsigned int* __restrict__ bbox) {
  __shared__ unsigned int rmn[3][4], rmx[3][4];
  int tid = threadIdx.x;
  int t = blockIdx.x*256 + tid;
  int b = t >> 15, n = t & (NPTS-1);
  const float* cb = coords + (size_t)b*(NPTS*3);
  unsigned int e[3] = { encf(cb[n*3+0]), encf(cb[n*3+1]), encf(cb[n*3+2]) };
  unsigned int mn[3] = { e[0], e[1], e[2] }, mx[3] = { e[0], e[1], e[2] };
#pragma unroll
  for (int s = 32; s > 0; s >>= 1) {
#pragma unroll
    for (int a = 0; a < 3; ++a) {
      unsigned int o1 = (unsigned int)__shfl_xor((int)mn[a], s, 64);
      unsigned int o2 = (unsigned int)__shfl_xor((int)mx[a], s, 64);
      mn[a] = mn[a] < o1 ? mn[a] : o1;
      mx[a] = mx[a] > o2 ? mx[a] : o2;
    }
  }
  int wave = tid >> 6, lane = tid & 63;
  if (lane == 0) {
#pragma unroll
    for (int a = 0; a < 3; ++a) { rmn[a][wave] = mn[a]; rmx[a][wave] = mx[a]; }
  }
  __syncthreads();
  if (tid < 3) {
    unsigned int a0 = min(min(rmn[tid][0], rmn[tid][1]), min(rmn[tid][2], rmn[tid][3]));
    unsigned int A0 = max(max(rmx[tid][0], rmx[tid][1]), max(rmx[tid][2], rmx[tid][3]));
    atomicMin(&bbox[b*6 + tid], a0);
    atomicMax(&bbox[b*6 + 3 + tid], A0);
  }
}

// ---------------- per-axis fine histogram ----------------
__global__ void k_hist(const float* __restrict__ coords, const unsigned int* __restrict__ bbox,
                       int* __restrict__ hist) {
  int t = blockIdx.x*256 + threadIdx.x;
  int b = t >> 15, n = t & (NPTS-1);
  const float* cb = coords + (size_t)b*(NPTS*3);
#pragma unroll
  for (int a = 0; a < 3; ++a) {
    float l = decf(bbox[b*6+a]), h = decf(bbox[b*6+3+a]);
    float ex = (h - l)*(1.f + 4e-7f) + 1e-30f;
    float inv = (float)HB/ex;
    int bin = (int)((cb[n*3+a] - l)*inv);
    bin = min(HB-1, max(0, bin));
    atomicAdd(&hist[(b*3+a)*HB + bin], 1);
  }
}

// ---------------- equal-frequency edges from histogram cdf ----------------
__global__ void k_edges(const int* __restrict__ hist, const unsigned int* __restrict__ bbox,
                        float* __restrict__ edges) {
  __shared__ int part[256];
  int p = blockIdx.x;                 // pair = b*3 + a, 6 blocks
  int b = p/3, a = p - b*3;
  int tid = threadIdx.x;
  const int* h = hist + p*HB;
  int v[8]; int s = 0;
#pragma unroll
  for (int i = 0; i < 8; ++i) { v[i] = h[tid*8 + i]; s += v[i]; }
  part[tid] = s;
  __syncthreads();
  for (int off = 1; off < 256; off <<= 1) {
    int x = part[tid];
    int y = (tid >= off) ? part[tid-off] : 0;
    __syncthreads();
    part[tid] = x + y;
    __syncthreads();
  }
  float l = decf(bbox[b*6+a]), hi = decf(bbox[b*6+3+a]);
  float ex = (hi - l)*(1.f + 4e-7f) + 1e-30f;
  float bw = ex*(1.f/(float)HB);
  int c = part[tid] - s;              // exclusive base
#pragma unroll
  for (int i = 0; i < 8; ++i) {
    int lo_c = c; c += v[i];
#pragma unroll
    for (int g = 1; g < G; ++g) {
      int tq = g*(NPTS/G);
      if (lo_c < tq && c >= tq) edges[p*(G+1) + g] = l + bw*(float)(tid*8 + i + 1);
    }
  }
  if (tid == 0) { edges[p*(G+1)] = l; edges[p*(G+1) + G] = hi + fabsf(hi)*1e-6f + 1e-20f; }
}

// ---------------- bin points into quantile cells ----------------
__global__ void k_bin(const float* __restrict__ coords, const float* __restrict__ edges,
                      int* __restrict__ cellid, int* __restrict__ gcnt) {
  __shared__ float se[3][G+1];
  int tid = threadIdx.x;
  int t = blockIdx.x*256 + tid;
  int b = t >> 15, n = t & (NPTS-1);
  if (tid < 3*(G+1)) se[tid/(G+1)][tid%(G+1)] = edges[b*3*(G+1) + tid];
  __syncthreads();
  const float* cb = coords + (size_t)b*(NPTS*3);
  int c0 = bs16(se[0], cb[n*3+0]);
  int c1 = bs16(se[1], cb[n*3+1]);
  int c2 = bs16(se[2], cb[n*3+2]);
  int cid = b*G3 + (c2*G + c1)*G + c0;
  cellid[t] = cid;
  atomicAdd(&gcnt[cid], 1);
}

// ---------------- deterministic global scan over all 8192 cells ----------------
// writes gstart (mutated by scatter) AND starts (+sentinel, read by knn)
__global__ void k_alloc(const int* __restrict__ gcnt, int* __restrict__ gstart,
                        int* __restrict__ starts) {
  __shared__ int part[1024];
  int tid = threadIdx.x;
  int v[8]; int s = 0;
#pragma unroll
  for (int i = 0; i < 8; ++i) { v[i] = gcnt[tid*8 + i]; s += v[i]; }
  part[tid] = s;
  __syncthreads();
  for (int off = 1; off < 1024; off <<= 1) {
    int x = part[tid];
    int y = (tid >= off) ? part[tid-off] : 0;
    __syncthreads();
    part[tid] = x + y;
    __syncthreads();
  }
  int base = part[tid] - s;
#pragma unroll
  for (int i = 0; i < 8; ++i) { gstart[tid*8 + i] = base; starts[tid*8 + i] = base; base += v[i]; }
  if (tid == 1023) starts[2*G3] = NQ;
}

// ---------------- scatter: packed float4 + original id, cell-sorted ----------------
__global__ void k_scatter(const float* __restrict__ coords, const int* __restrict__ cellid,
                          int* __restrict__ gstart, float4* __restrict__ csort,
                          int* __restrict__ sortid) {
  int t = blockIdx.x*256 + threadIdx.x;
  int b = t >> 15, n = t & (NPTS-1);
  const float* cb = coords + (size_t)b*(NPTS*3);
  int cid = cellid[t];
  int pos = atomicAdd(&gstart[cid], 1);
  float x = cb[n*3+0], y = cb[n*3+1], z = cb[n*3+2];
  csort[pos] = make_float4(x, y, z, x*x + y*y + z*z);
  sortid[pos] = n;
}

// ---------------- exact KNN: one wave/query, two-pass threshold+compaction ----------------
__launch_bounds__(256)
__global__ void k_knn_grid(const float4* __restrict__ csort, const int* __restrict__ sortid,
                           const int* __restrict__ starts, const float* __restrict__ edges,
                           int* __restrict__ oidx) {
  __shared__ int   ls[G3+1];                // per-batch cell-range table (16.4 KB)
  __shared__ float se[3][G+1];
  __shared__ float sbd[4][CAP];             // per-wave candidate buffer (8 KB total)
  __shared__ int   sbi[4][CAP];
  int tid = threadIdx.x;
  int lane = tid & 63;
  int w = tid >> 6;
  int t = blockIdx.x*4 + w;                 // one wave = one query (sorted position)
  int b = t >> 15;                          // 4 | 32768 -> uniform per block
  if (tid < 3*(G+1)) se[tid/(G+1)][tid%(G+1)] = edges[b*3*(G+1) + tid];
  for (int i = tid; i <= G3; i += 256) ls[i] = starts[b*G3 + i];
  __syncthreads();
  float4 qv = csort[t];                     // broadcast
  const float qx = qv.x, qy = qv.y, qz = qv.z, qsq = qv.w;
  const int cx = bs16(se[0], qx), cy = bs16(se[1], qy), cz = bs16(se[2], qz);

  // ---- pass 1: per-lane min only, shell walk with provable termination ----
  float mn = 1e30f;
  int r_end = G + 1;
  for (int r = 0; r <= G; ++r) {
    if (r >= 1) {
      int rm = r - 1;
      if (cx-rm <= 0 && cx+rm >= G-1 && cy-rm <= 0 && cy+rm >= G-1 &&
          cz-rm <= 0 && cz+rm >= G-1) { r_end = r; break; }     // searched everything
      float bound = kth16(mn, lane);        // 16 distinct candidates <= bound => d16 <= bound
      if (bound < 1e29f) {
        float m = 1e30f;
        if (cx-rm > 0)   m = fminf(m, qx - se[0][cx-rm]);
        if (cx+rm < G-1) m = fminf(m, se[0][cx+rm+1] - qx);
        if (cy-rm > 0)   m = fminf(m, qy - se[1][cy-rm]);
        if (cy+rm < G-1) m = fminf(m, se[1][cy+rm+1] - qy);
        if (cz-rm > 0)   m = fminf(m, qz - se[2][cz-rm]);
        if (cz+rm < G-1) m = fminf(m, se[2][cz+rm+1] - qz);
        if (m > 0.f && m*m > bound + SLOP) { r_end = r; break; }
      }
    }
    int zlo = max(cz-r, 0), zhi = min(cz+r, G-1);
    for (int z = zlo; z <= zhi; ++z) {
      bool zf = (z == cz-r) || (z == cz+r);
      int ylo = max(cy-r, 0), yhi = min(cy+r, G-1);
      for (int y = ylo; y <= yhi; ++y) {
        bool yf = (y == cy-r) || (y == cy+r);
        int xa, xb;
        if (zf || yf) { xa = max(cx-r, 0); xb = min(cx+r, G-1); }
        else if (cx-r >= 0) { xa = cx-r; xb = (cx+r <= G-1) ? cx-r : cx-r; }
        else { xa = cx+r; xb = cx+r; }
        // handle the two-sided interior case
        int c0 = (z*G + y)*G + xa;
        int s0 = ls[c0], e0 = ls[c0 + (xb - xa) + 1];
        for (int i = s0 + lane; i < e0; i += 64) {
          float4 p = csort[i];
          float d = qsq + p.w - 2.f*(qx*p.x + qy*p.y + qz*p.z);
          mn = fminf(mn, d);
        }
        if (!zf && !yf && cx-r >= 0 && cx+r <= G-1) {   // interior row: second side
          int c1 = (z*G + y)*G + (cx+r);
          int s1 = ls[c1], e1 = ls[c1 + 1];
          for (int i = s1 + lane; i < e1; i += 64) {
            float4 p = csort[i];
            float d = qsq + p.w - 2.f*(qx*p.x + qy*p.y + qz*p.z);
            mn = fminf(mn, d);
          }
        }
      }
    }
  }
  float T = kth16(mn, lane) + TEPS;         // upper bound on d16 (+ fp slack)

  // ---- pass 2: re-walk, compact candidates with d <= T into LDS ----
  int cnt = 0;
  for (int r = 0; r < r_end; ++r) {
    int zlo = max(cz-r, 0), zhi = min(cz+r, G-1);
    for (int z = zlo; z <= zhi; ++z) {
      bool zf = (z == cz-r) || (z == cz+r);
      int ylo = max(cy-r, 0), yhi = min(cy+r, G-1);
      for (int y = ylo; y <= yhi; ++y) {
        bool yf = (y == cy-r) || (y == cy+r);
#pragma unroll 1
        for (int side = 0; side < 2; ++side) {
          int xa, xb;
          if (zf || yf) { if (side) break; xa = max(cx-r, 0); xb = min(cx+r, G-1); }
          else {
            if (side == 0) { if (cx-r < 0) continue; xa = xb = cx-r; }
            else           { if (cx+r > G-1) continue; xa = xb = cx+r; }
          }
          int c0 = (z*G + y)*G + xa;
          int s0 = ls[c0], e0 = ls[c0 + (xb - xa) + 1];
          int len = e0 - s0;
          for (int base2 = 0; base2 < len; base2 += 64) {
            int i = s0 + base2 + lane;
            bool valid = (base2 + lane) < len;
            float d = 1e30f;
            if (valid) {
              float4 p = csort[i];
              d = qsq + p.w - 2.f*(qx*p.x + qy*p.y + qz*p.z);
            }
            bool take = valid && (d <= T);
            unsigned long long bal = __ballot(take);
            int pos = cnt + __popcll(bal & ((1ull << lane) - 1ull));
            if (take && pos < CAP) { sbd[w][pos] = d; sbi[w][pos] = i; }
            cnt += __popcll(bal);
          }
        }
      }
    }
  }

  int qn = sortid[t];
  size_t row = ((size_t)(b*NPTS + qn))*KK;

  if (cnt <= 64) {
    // ---- normal path: 64-lane bitonic sort of (d, idx) pairs ----
    float dv = (lane < cnt) ? sbd[w][lane] : 1e30f;
    int   iv = (lane < cnt) ? sbi[w][lane] : 0x7fffffff;
#pragma unroll
    for (int k2 = 2; k2 <= 64; k2 <<= 1) {
#pragma unroll
      for (int j = k2 >> 1; j > 0; j >>= 1) {
        float od = __shfl_xor(dv, j, 64);
        int   oi = __shfl_xor(iv, j, 64);
        bool keepmin = (((lane & j) == 0) == ((lane & k2) == 0));
        bool less = (od < dv) || (od == dv && oi < iv);
        bool take2 = keepmin ? less : !less;
        dv = take2 ? od : dv;
        iv = take2 ? oi : iv;
      }
    }
    if (lane < KK) oidx[row + lane] = sortid[iv];
  } else if (cnt <= CAP) {
    // ---- extraction path: 16 rounds over strided LDS entries ----
    int res = 0;
#pragma unroll
    for (int r = 0; r < KK; ++r) {
      float lm = 1e30f; int li = 0x7fffffff; int le = -1;
      for (int e2 = lane; e2 < cnt; e2 += 64) {
        float v = sbd[w][e2];
        int   i2 = sbi[w][e2];
        bool bet = (v < lm) || (v == lm && i2 < li);
        lm = bet ? v : lm; li = bet ? i2 : li; le = bet ? e2 : le;
      }
#pragma unroll
      for (int m = 1; m < 64; m <<= 1) {
        float ov = __shfl_xor(lm, m, 64);
        int   oi = __shfl_xor(li, m, 64);
        int   oe = __shfl_xor(le, m, 64);
        bool bet = (ov < lm) || (ov == lm && oi < li);
        lm = bet ? ov : lm; li = bet ? oi : li; le = bet ? oe : le;
      }
      if (lane == r) res = li;
      if (lane == 0) sbd[w][le] = 1e30f;   // mark winner used
    }
    if (lane < KK) oidx[row + lane] = sortid[res];
  } else {
    // ---- overflow fallback (provably exact, ~never taken): full insert scan ----
    float dl[KK]; int il[KK];
#pragma unroll
    for (int i = 0; i < KK; ++i) { dl[i] = 1e30f; il[i] = 0; }
    for (int r = 0; r < r_end; ++r) {
      int zlo = max(cz-r, 0), zhi = min(cz+r, G-1);
      for (int z = zlo; z <= zhi; ++z) {
        bool zf = (z == cz-r) || (z == cz+r);
        int ylo = max(cy-r, 0), yhi = min(cy+r, G-1);
        for (int y = ylo; y <= yhi; ++y) {
          bool yf = (y == cy-r) || (y == cy+r);
#pragma unroll 1
          for (int side = 0; side < 2; ++side) {
            int xa, xb;
            if (zf || yf) { if (side) break; xa = max(cx-r, 0); xb = min(cx+r, G-1); }
            else {
              if (side == 0) { if (cx-r < 0) continue; xa = xb = cx-r; }
              else           { if (cx+r > G-1) continue; xa = xb = cx+r; }
            }
            int c0 = (z*G + y)*G + xa;
            int s0 = ls[c0], e0 = ls[c0 + (xb - xa) + 1];
            for (int i = s0 + lane; i < e0; i += 64) {
              float4 p = csort[i];
              float d = qsq + p.w - 2.f*(qx*p.x + qy*p.y + qz*p.z);
              if (d < dl[KK-1]) {
                float cd = d; int ci = i;
#pragma unroll
                for (int i2 = 0; i2 < KK; ++i2) {
                  bool sw = cd < dl[i2];
                  float td = dl[i2]; int ti = il[i2];
                  dl[i2] = sw ? cd : td; il[i2] = sw ? ci : ti;
                  cd = sw ? td : cd;    ci = sw ? ti : ci;
                }
              }
            }
          }
        }
      }
    }
    int res = 0;
#pragma unroll
    for (int r = 0; r < KK; ++r) {
      float v = dl[0]; int l = lane;
#pragma unroll
      for (int m = 1; m < 64; m <<= 1) {
        float ov = __shfl_xor(v, m, 64);
        int   ol = __shfl_xor(l, m, 64);
        bool take2 = (ov < v) || (ov == v && ol < l);
        v = take2 ? ov : v;
        l = take2 ? ol : l;
      }
      int wi = __shfl(il[0], l, 64);
      if (lane == r) res = wi;
      bool win = (lane == l);
#pragma unroll
      for (int i = 0; i < KK-1; ++i) {
        dl[i] = win ? dl[i+1] : dl[i];
        il[i] = win ? il[i+1] : il[i];
      }
      dl[KK-1] = win ? 1e30f : dl[KK-1];
    }
    if (lane < KK) oidx[row + lane] = sortid[res];
  }
}

// ---------------- mlp1 (leaky 0.2) + shortcut BN stats ----------------
__global__ void k_mlp1(const float* __restrict__ features,
                       const float* __restrict__ W1, const float* __restrict__ b1,
                       const float* __restrict__ Wsc, const float* __restrict__ bsc,
                       float* __restrict__ x1, float* __restrict__ stats) {
  __shared__ float sW1[128], sb1[16], sWsc[512], sbsc[64];
  int tid = threadIdx.x;
  if (tid < 128) sW1[tid] = W1[tid];
  if (tid < 16)  sb1[tid] = b1[tid];
  if (tid < 64)  sbsc[tid] = bsc[tid];
  for (int i = tid; i < 512; i += 256) sWsc[i] = Wsc[i];
  __syncthreads();
  int q = blockIdx.x*256 + tid;
  int b = q >> 15, n = q & (NPTS-1);
  float f[8];
#pragma unroll
  for (int c = 0; c < 8; ++c) f[c] = features[((size_t)b*8 + c)*NPTS + n];
#pragma unroll
  for (int co = 0; co < 16; ++co) {
    float a = sb1[co];
#pragma unroll
    for (int c = 0; c < 8; ++c) a += f[c]*sW1[co*8+c];
    x1[(size_t)q*16 + co] = a > 0.f ? a : 0.2f*a;
  }
  int lane = tid & 63;
#pragma unroll
  for (int co = 0; co < 64; ++co) {
    float a = sbsc[co];
#pragma unroll
    for (int c = 0; c < 8; ++c) a += f[c]*sWsc[co*8+c];
    float s = wred64(a), ss = wred64(a*a);
    if (lane == 0) { atomicAdd(&stats[S_SC+co], s); atomicAdd(&stats[S_SC+64+co], ss); }
  }
}

// ---------------- BN stats for BOTH LSE geometric encodings ----------------
__global__ void k_lsestats(const float* __restrict__ coords, const int* __restrict__ idx,
                           const float* __restrict__ Wl1, const float* __restrict__ bl1,
                           const float* __restrict__ Wl2, const float* __restrict__ bl2,
                           float* __restrict__ stats) {
  __shared__ float sW1[160], sb1[16], sW2[160], sb2[16];
  __shared__ float red[4][64];
  int tid = threadIdx.x;
  for (int i = tid; i < 160; i += 256) { sW1[i] = Wl1[i]; sW2[i] = Wl2[i]; }
  if (tid < 16) { sb1[tid] = bl1[tid]; sb2[tid] = bl2[tid]; }
  __syncthreads();
  int t = blockIdx.x*256 + tid;         // (b,n,k) flat
  int q = t >> 4;
  int b = q >> 15, n = q & (NPTS-1);
  const float* cb = coords + (size_t)b*(NPTS*3);
  int j = idx[t];
  float cx = cb[n*3], cy = cb[n*3+1], cz = cb[n*3+2];
  float px = cb[j*3], py = cb[j*3+1], pz = cb[j*3+2];
  float cat[10] = {cx,cy,cz,px,py,pz,cx-px,cy-py,cz-pz,1.f};
  int wave = tid >> 6, lane = tid & 63;
#pragma unroll
  for (int co = 0; co < 16; ++co) {
    float a1 = sb1[co], a2 = sb2[co];
#pragma unroll
    for (int d0 = 0; d0 < 10; ++d0) { a1 += cat[d0]*sW1[co*10+d0]; a2 += cat[d0]*sW2[co*10+d0]; }
    float s1 = wred64(a1), q1 = wred64(a1*a1);
    float s2 = wred64(a2), q2 = wred64(a2*a2);
    if (lane == 0) { red[wave][co]=s1; red[wave][16+co]=q1; red[wave][32+co]=s2; red[wave][48+co]=q2; }
  }
  __syncthreads();
  if (tid < 64) {
    float v = red[0][tid] + red[1][tid] + red[2][tid] + red[3][tid];
    int grp = tid >> 4, c = tid & 15;
    int off = (grp == 0) ? (S_L1 + c) : (grp == 1) ? (S_L1 + 16 + c)
            : (grp == 2) ? (S_L2 + c) : (S_L2 + 16 + c);
    atomicAdd(&stats[off], v);
  }
}

// ---------------- BN finalize ----------------
__global__ void k_bnfin(const float* __restrict__ stats, float* __restrict__ coef,
                        const float* __restrict__ gam, const float* __restrict__ bet,
                        int soff, int coff, int nch, float invc) {
  int c = threadIdx.x;
  if (c < nch) {
    float m = stats[soff + c]*invc;
    float v = stats[soff + nch + c]*invc - m*m;
    float a = gam[c]*rsqrtf(v + EPS);
    coef[coff + c] = a;
    coef[coff + nch + c] = bet[c] - m*a;
  }
}

// ---------------- LSE1 + attentive pooling 1 ----------------
__launch_bounds__(256)
__global__ void k_att1(const float* __restrict__ coords, const int* __restrict__ idx,
                       const float* __restrict__ x1ws,
                       const float* __restrict__ Wl1, const float* __restrict__ bl1,
                       const float* __restrict__ Ws1, const float* __restrict__ Wp1,
                       const float* __restrict__ bp1, const float* __restrict__ coef,
                       float* __restrict__ t2, float* __restrict__ stats) {
  __shared__ float sWl[160], sbl[16];
  __shared__ float sWs[1024];
  __shared__ float sWpT[512], sbp[16];
  __shared__ float lsum[16], lsq[16];
  int tid = threadIdx.x;
  for (int i = tid; i < 160; i += 256) { int c = i/10; sWl[i] = Wl1[i]*coef[C_L1 + c]; }
  if (tid < 16) sbl[tid] = bl1[tid]*coef[C_L1+tid] + coef[C_L1+16+tid];
  for (int i = tid; i < 1024; i += 256) sWs[i] = Ws1[i];
  for (int i = tid; i < 512; i += 256) { int co = i >> 4, cp = i & 15; sWpT[i] = Wp1[cp*32 + co]; }
  if (tid < 16) { sbp[tid] = bp1[tid]; lsum[tid] = 0.f; lsq[tid] = 0.f; }
  __syncthreads();
  int gp = blockIdx.x*16 + (tid >> 4);
  int k  = tid & 15;
  int b = gp >> 15, n = gp & (NPTS-1);
  const float* cb = coords + (size_t)b*(NPTS*3);
  int j = idx[(size_t)gp*KK + k];
  float cx = cb[n*3], cy = cb[n*3+1], cz = cb[n*3+2];
  float px = cb[j*3], py = cb[j*3+1], pz = cb[j*3+2];
  float cat[10] = {cx,cy,cz,px,py,pz,cx-px,cy-py,cz-pz,1.f};
  float x[32];
#pragma unroll
  for (int co = 0; co < 16; ++co) {
    float a = sbl[co];
#pragma unroll
    for (int d0 = 0; d0 < 10; ++d0) a += cat[d0]*sWl[co*10+d0];
    x[co] = a > 0.f ? a : 0.f;
  }
  {
    const float4* xp = (const float4*)(x1ws + (size_t)gp*16);
    float4 u0 = xp[0], u1 = xp[1], u2 = xp[2], u3 = xp[3];
    x[16]=u0.x; x[17]=u0.y; x[18]=u0.z; x[19]=u0.w;
    x[20]=u1.x; x[21]=u1.y; x[22]=u1.z; x[23]=u1.w;
    x[24]=u2.x; x[25]=u2.y; x[26]=u2.z; x[27]=u2.w;
    x[28]=u3.x; x[29]=u3.y; x[30]=u3.z; x[31]=u3.w;
  }
  float tacc = sbp[k];
#pragma unroll
  for (int co = 0; co < 32; ++co) {
    float s = 0.f;
#pragma unroll
    for (int ci = 0; ci < 32; ++ci) s += x[ci]*sWs[co*32+ci];
    float m = s;
#pragma unroll
    for (int msk = 8; msk > 0; msk >>= 1) m = fmaxf(m, __shfl_xor(m, msk, 16));
    float e = __expf(s - m);
    float se = e;
#pragma unroll
    for (int msk = 8; msk > 0; msk >>= 1) se += __shfl_xor(se, msk, 16);
    float w = e/se;
    float fv = w*x[co];
#pragma unroll
    for (int msk = 8; msk > 0; msk >>= 1) fv += __shfl_xor(fv, msk, 16);
    tacc += fv*sWpT[co*16+k];
  }
  t2[(size_t)gp*16 + k] = tacc;
  atomicAdd(&lsum[k], tacc);
  atomicAdd(&lsq[k], tacc*tacc);
  __syncthreads();
  if (tid < 16) { atomicAdd(&stats[S_P1+tid], lsum[tid]); atomicAdd(&stats[S_P1+16+tid], lsq[tid]); }
}

// ---------------- LSE2 + attentive pooling 2 ----------------
__launch_bounds__(256)
__global__ void k_att2(const float* __restrict__ coords, const int* __restrict__ idx,
                       const float* __restrict__ t2ws,
                       const float* __restrict__ Wl2, const float* __restrict__ bl2,
                       const float* __restrict__ Ws2, const float* __restrict__ Wp2,
                       const float* __restrict__ bp2, const float* __restrict__ coef,
                       float* __restrict__ t4, float* __restrict__ stats) {
  __shared__ float sWl[160], sbl[16];
  __shared__ float sWs[1024];
  __shared__ float sWpT[1024], sbp[32];
  __shared__ float sa1[16], sc1[16];
  __shared__ float lsum[32], lsq[32];
  int tid = threadIdx.x;
  for (int i = tid; i < 160; i += 256) { int c = i/10; sWl[i] = Wl2[i]*coef[C_L2 + c]; }
  if (tid < 16) sbl[tid] = bl2[tid]*coef[C_L2+tid] + coef[C_L2+16+tid];
  for (int i = tid; i < 1024; i += 256) {
    sWs[i] = Ws2[i];
    int co = i >> 5, cp = i & 31; sWpT[i] = Wp2[cp*32 + co];
  }
  if (tid < 32) { sbp[tid] = bp2[tid]; lsum[tid]=0.f; lsq[tid]=0.f; }
  if (tid < 16) { sa1[tid] = coef[C_P1+tid]; sc1[tid] = coef[C_P1+16+tid]; }
  __syncthreads();
  int gp = blockIdx.x*16 + (tid >> 4);
  int k  = tid & 15;
  int b = gp >> 15, n = gp & (NPTS-1);
  const float* cb = coords + (size_t)b*(NPTS*3);
  int j = idx[(size_t)gp*KK + k];
  float cx = cb[n*3], cy = cb[n*3+1], cz = cb[n*3+2];
  float px = cb[j*3], py = cb[j*3+1], pz = cb[j*3+2];
  float cat[10] = {cx,cy,cz,px,py,pz,cx-px,cy-py,cz-pz,1.f};
  float x[32];
#pragma unroll
  for (int co = 0; co < 16; ++co) {
    float a = sbl[co];
#pragma unroll
    for (int d0 = 0; d0 < 10; ++d0) a += cat[d0]*sWl[co*10+d0];
    x[co] = a > 0.f ? a : 0.f;
  }
  {
    const float4* xp = (const float4*)(t2ws + (size_t)gp*16);
    float4 u0 = xp[0], u1 = xp[1], u2 = xp[2], u3 = xp[3];
    float xv[16] = {u0.x,u0.y,u0.z,u0.w, u1.x,u1.y,u1.z,u1.w,
                    u2.x,u2.y,u2.z,u2.w, u3.x,u3.y,u3.z,u3.w};
#pragma unroll
    for (int c = 0; c < 16; ++c) {
      float v = xv[c]*sa1[c] + sc1[c];
      x[16+c] = v > 0.f ? v : 0.f;
    }
  }
  float tacc0 = sbp[k], tacc1 = sbp[k+16];
#pragma unroll
  for (int co = 0; co < 32; ++co) {
    float s = 0.f;
#pragma unroll
    for (int ci = 0; ci < 32; ++ci) s += x[ci]*sWs[co*32+ci];
    float m = s;
#pragma unroll
    for (int msk = 8; msk > 0; msk >>= 1) m = fmaxf(m, __shfl_xor(m, msk, 16));
    float e = __expf(s - m);
    float se = e;
#pragma unroll
    for (int msk = 8; msk > 0; msk >>= 1) se += __shfl_xor(se, msk, 16);
    float w = e/se;
    float fv = w*x[co];
#pragma unroll
    for (int msk = 8; msk > 0; msk >>= 1) fv += __shfl_xor(fv, msk, 16);
    tacc0 += fv*sWpT[co*32+k];
    tacc1 += fv*sWpT[co*32+k+16];
  }
  t4[(size_t)gp*32 + k]      = tacc0;
  t4[(size_t)gp*32 + k + 16] = tacc1;
  atomicAdd(&lsum[k], tacc0);      atomicAdd(&lsq[k], tacc0*tacc0);
  atomicAdd(&lsum[k+16], tacc1);   atomicAdd(&lsq[k+16], tacc1*tacc1);
  __syncthreads();
  if (tid < 32) { atomicAdd(&stats[S_P2+tid], lsum[tid]); atomicAdd(&stats[S_P2+32+tid], lsq[tid]); }
}

// ---------------- final: mlp2 + BN'd shortcut + leaky 0.01 ----------------
__global__ void k_final(const float* __restrict__ t4ws, const float* __restrict__ features,
                        const float* __restrict__ W2, const float* __restrict__ b2,
                        const float* __restrict__ Wsc, const float* __restrict__ bsc,
                        const float* __restrict__ coef, float* __restrict__ out) {
  __shared__ float sW2[2048], sb2[64], sWscF[512], sbscF[64], sa[32], scc[32];
  int tid = threadIdx.x;
  for (int i = tid; i < 2048; i += 256) sW2[i] = W2[i];
  if (tid < 64) sb2[tid] = b2[tid];
  for (int i = tid; i < 512; i += 256) { int c2 = i >> 3; sWscF[i] = Wsc[i]*coef[C_SC + c2]; }
  if (tid < 64) sbscF[tid] = bsc[tid]*coef[C_SC+tid] + coef[C_SC+64+tid];
  if (tid < 32) { sa[tid] = coef[C_P2+tid]; scc[tid] = coef[C_P2+32+tid]; }
  __syncthreads();
  int q = blockIdx.x*256 + tid;
  int b = q >> 15, n = q & (NPTS-1);
  float x3[32];
  const float4* tp = (const float4*)(t4ws + (size_t)q*32);
#pragma unroll
  for (int i = 0; i < 8; ++i) {
    float4 u = tp[i];
    float v0 = u.x*sa[4*i+0] + scc[4*i+0];
    float v1 = u.y*sa[4*i+1] + scc[4*i+1];
    float v2 = u.z*sa[4*i+2] + scc[4*i+2];
    float v3 = u.w*sa[4*i+3] + scc[4*i+3];
    x3[4*i+0] = v0 > 0.f ? v0 : 0.f;
    x3[4*i+1] = v1 > 0.f ? v1 : 0.f;
    x3[4*i+2] = v2 > 0.f ? v2 : 0.f;
    x3[4*i+3] = v3 > 0.f ? v3 : 0.f;
  }
  float f[8];
#pragma unroll
  for (int c = 0; c < 8; ++c) f[c] = features[((size_t)b*8+c)*NPTS + n];
  for (int c2 = 0; c2 < 64; ++c2) {
    float acc = sb2[c2];
#pragma unroll
    for (int co = 0; co < 32; ++co) acc += x3[co]*sW2[c2*32+co];
    float sv = sbscF[c2];
#pragma unroll
    for (int c = 0; c < 8; ++c) sv += f[c]*sWscF[c2*8+c];
    float o = acc + sv;
    out[((size_t)b*64 + c2)*NPTS + n] = o > 0.f ? o : 0.01f*o;
  }
}

extern "C" void kernel_launch(void* const* d_in, const int* in_sizes, int n_in,
                              void* d_out, int out_size, void* d_ws, size_t ws_size,
                              hipStream_t stream) {
  const float* coords   = (const float*)d_in[0];
  const float* features = (const float*)d_in[1];
  const float* W1  = (const float*)d_in[2];
  const float* b1  = (const float*)d_in[3];
  const float* Wl1 = (const float*)d_in[4];
  const float* bl1 = (const float*)d_in[5];
  const float* gl1 = (const float*)d_in[6];
  const float* bl1b= (const float*)d_in[7];
  const float* Ws1 = (const float*)d_in[8];
  const float* Wp1 = (const float*)d_in[9];
  const float* bp1 = (const float*)d_in[10];
  const float* gp1 = (const float*)d_in[11];
  const float* bp1b= (const float*)d_in[12];
  const float* Wl2 = (const float*)d_in[13];
  const float* bl2 = (const float*)d_in[14];
  const float* gl2 = (const float*)d_in[15];
  const float* bl2b= (const float*)d_in[16];
  const float* Ws2 = (const float*)d_in[17];
  const float* Wp2 = (const float*)d_in[18];
  const float* bp2 = (const float*)d_in[19];
  const float* gp2 = (const float*)d_in[20];
  const float* bp2b= (const float*)d_in[21];
  const float* W2  = (const float*)d_in[22];
  const float* b2  = (const float*)d_in[23];
  const float* Wsc = (const float*)d_in[24];
  const float* bsc = (const float*)d_in[25];
  const float* gsc = (const float*)d_in[26];
  const float* bscb= (const float*)d_in[27];

  float* wsF  = (float*)d_ws;
  int*   wsI  = (int*)d_ws;
  int*   idxp = wsI;
  float* x1p  = wsF + WS_X1;
  float* t2p  = wsF + WS_T2;
  float* t4p  = wsF + WS_T4;
  float* stat = wsF + WS_STAT;
  float* coef = wsF + WS_COEF;
  int*   gcnt = wsI + WS_GCNT;
  int*   gsta = wsI + WS_GSTART;
  int*   gcel = wsI + WS_CELLID;
  int*   sid  = wsI + WS_SORTID;
  float4* csrt = (float4*)(wsF + WS_CSORT);
  unsigned int* bbox = (unsigned int*)(wsI + WS_BBOX);
  int*   hist = wsI + WS_HIST;
  int*   strt = wsI + WS_STARTS;          // aliases hist (dead after k_edges)
  float* edge = wsF + WS_EDGE;
  float* outp = (float*)d_out;

  hipLaunchKernelGGL(k_zero_all, dim3(48), dim3(256), 0, stream, stat, gcnt, hist, bbox);
  hipLaunchKernelGGL(k_bbox,    dim3(NQ/256), dim3(256), 0, stream, coords, bbox);
  hipLaunchKernelGGL(k_hist,    dim3(NQ/256), dim3(256), 0, stream, coords, bbox, hist);
  hipLaunchKernelGGL(k_edges,   dim3(6), dim3(256), 0, stream, hist, bbox, edge);
  hipLaunchKernelGGL(k_bin,     dim3(NQ/256), dim3(256), 0, stream, coords, edge, gcel, gcnt);
  hipLaunchKernelGGL(k_alloc,   dim3(1), dim3(1024), 0, stream, gcnt, gsta, strt);
  hipLaunchKernelGGL(k_scatter, dim3(NQ/256), dim3(256), 0, stream, coords, gcel, gsta, csrt, sid);
  hipLaunchKernelGGL(k_knn_grid,dim3(NQ/4), dim3(256), 0, stream,
                     csrt, sid, strt, edge, idxp);
  hipLaunchKernelGGL(k_mlp1, dim3(NQ/256), dim3(256), 0, stream,
                     features, W1, b1, Wsc, bsc, x1p, stat);
  hipLaunchKernelGGL(k_lsestats, dim3((NQ*KK)/256), dim3(256), 0, stream,
                     coords, idxp, Wl1, bl1, Wl2, bl2, stat);
  hipLaunchKernelGGL(k_bnfin, dim3(1), dim3(64), 0, stream, stat, coef, gl1, bl1b,
                     S_L1, C_L1, 16, 1.f/(float)((size_t)NQ*KK));
  hipLaunchKernelGGL(k_bnfin, dim3(1), dim3(64), 0, stream, stat, coef, gl2, bl2b,
                     S_L2, C_L2, 16, 1.f/(float)((size_t)NQ*KK));
  hipLaunchKernelGGL(k_bnfin, dim3(1), dim3(64), 0, stream, stat, coef, gsc, bscb,
                     S_SC, C_SC, 64, 1.f/(float)NQ);
  hipLaunchKernelGGL(k_att1, dim3(NQ/16), dim3(256), 0, stream,
                     coords, idxp, x1p, Wl1, bl1, Ws1, Wp1, bp1, coef, t2p, stat);
  hipLaunchKernelGGL(k_bnfin, dim3(1), dim3(64), 0, stream, stat, coef, gp1, bp1b,
                     S_P1, C_P1, 16, 1.f/(float)NQ);
  hipLaunchKernelGGL(k_att2, dim3(NQ/16), dim3(256), 0, stream,
                     coords, idxp, t2p, Wl2, bl2, Ws2, Wp2, bp2, coef, t4p, stat);
  hipLaunchKernelGGL(k_bnfin, dim3(1), dim3(64), 0, stream, stat, coef, gp2, bp2b,
                     S_P2, C_P2, 32, 1.f/(float)NQ);
  hipLaunchKernelGGL(k_final, dim3(NQ/256), dim3(256), 0, stream,
                     t4p, features, W2, b2, Wsc, bsc, coef, outp);
}

// Round 8
// 2374.706 us; speedup vs baseline: 1.8151x; 1.8151x over previous
//
#include <hip/hip_runtime.h>
#include <math.h>

#define NPTS  32768
#define NB    2
#define NQ    (NB*NPTS)
#define KK    16
#define EPS   1e-6f
#define G     16
#define G3    (G*G*G)
#define HB    2048
#define SLOP  0.05f
#define CAPC  512

// stats / coef element offsets
#define S_L1 0
#define S_L2 32
#define S_P1 64
#define S_P2 96
#define S_SC 160
#define C_L1 0
#define C_L2 32
#define C_P1 64
#define C_P2 96
#define C_SC 160

// workspace element offsets (4-byte units)
#define WS_X1     (NQ*16)
#define WS_T2     (NQ*32)
#define WS_T4     (NQ*48)
#define WS_STAT   (NQ*80)
#define WS_COEF   (WS_STAT + 512)
#define WS_GCNT   (WS_STAT + 1024)
#define WS_GSTART (WS_GCNT + 2*G3)
#define WS_CELLID (WS_GSTART + 2*G3)
#define WS_SORTID (WS_CELLID + NQ)
#define WS_CSORT  (WS_SORTID + NQ)      /* float4 x NQ (16B-aligned) */
#define WS_BBOX   (WS_CSORT + 4*NQ)
#define WS_HIST   (WS_BBOX + 16)
#define WS_EDGE   (WS_HIST + 6*HB)
#define WS_STARTS WS_HIST               /* starts aliases hist (dead after k_edges) */
#define WS_FAIL   WS_CELLID             /* fail list aliases cellid (dead after scatter) */

__device__ __forceinline__ float wred64(float v) {
#pragma unroll
  for (int m = 32; m > 0; m >>= 1) v += __shfl_xor(v, m, 64);
  return v;
}

// order-preserving float <-> uint encoding for atomic min/max
__device__ __forceinline__ unsigned int encf(float f) {
  unsigned int u = __float_as_uint(f);
  return (u & 0x80000000u) ? ~u : (u | 0x80000000u);
}
__device__ __forceinline__ float decf(unsigned int u) {
  return (u & 0x80000000u) ? __uint_as_float(u & 0x7fffffffu) : __uint_as_float(~u);
}

// 4-step binary search over G=16 quantile edges; e[0] <= x guaranteed
__device__ __forceinline__ int bs16(const float* e, float x) {
  int c = (x >= e[8]) ? 8 : 0;
  c += (x >= e[c+4]) ? 4 : 0;
  c += (x >= e[c+2]) ? 2 : 0;
  c += (x >= e[c+1]) ? 1 : 0;
  return c;
}

// ---------------- zero stats + counters + hist + bbox + failcnt ----------------
__global__ void k_zero_all(float* __restrict__ stats, int* __restrict__ gcnt,
                           int* __restrict__ hist, unsigned int* __restrict__ bbox,
                           int* __restrict__ failcnt) {
  int i = blockIdx.x*256 + threadIdx.x;       // grid covers 12288
  if (i < 2*G3) gcnt[i] = 0;
  if (i < 6*HB) hist[i] = 0;
  if (i < 320)  stats[i] = 0.f;
  if (i < 12)   bbox[i] = ((i % 6) < 3) ? 0xFFFFFFFFu : 0u;
  if (i == 0)   failcnt[0] = 0;
}

// ---------------- per-batch exact bounding box ----------------
__global__ void k_bbox(const float* __restrict__ coords, unsigned int* __restrict__ bbox) {
  __shared__ unsigned int rmn[3][4], rmx[3][4];
  int tid = threadIdx.x;
  int t = blockIdx.x*256 + tid;
  int b = t >> 15, n = t & (NPTS-1);
  const float* cb = coords + (size_t)b*(NPTS*3);
  unsigned int e[3] = { encf(cb[n*3+0]), encf(cb[n*3+1]), encf(cb[n*3+2]) };
  unsigned int mn[3] = { e[0], e[1], e[2] }, mx[3] = { e[0], e[1], e[2] };
#pragma unroll
  for (int s = 32; s > 0; s >>= 1) {
#pragma unroll
    for (int a = 0; a < 3; ++a) {
      unsigned int o1 = (unsigned int)__shfl_xor((int)mn[a], s, 64);
      unsigned int o2 = (unsigned int)__shfl_xor((int)mx[a], s, 64);
      mn[a] = mn[a] < o1 ? mn[a] : o1;
      mx[a] = mx[a] > o2 ? mx[a] : o2;
    }
  }
  int wave = tid >> 6, lane = tid & 63;
  if (lane == 0) {
#pragma unroll
    for (int a = 0; a < 3; ++a) { rmn[a][wave] = mn[a]; rmx[a][wave] = mx[a]; }
  }
  __syncthreads();
  if (tid < 3) {
    unsigned int a0 = min(min(rmn[tid][0], rmn[tid][1]), min(rmn[tid][2], rmn[tid][3]));
    unsigned int A0 = max(max(rmx[tid][0], rmx[tid][1]), max(rmx[tid][2], rmx[tid][3]));
    atomicMin(&bbox[b*6 + tid], a0);
    atomicMax(&bbox[b*6 + 3 + tid], A0);
  }
}

// ---------------- per-axis fine histogram ----------------
__global__ void k_hist(const float* __restrict__ coords, const unsigned int* __restrict__ bbox,
                       int* __restrict__ hist) {
  int t = blockIdx.x*256 + threadIdx.x;
  int b = t >> 15, n = t & (NPTS-1);
  const float* cb = coords + (size_t)b*(NPTS*3);
#pragma unroll
  for (int a = 0; a < 3; ++a) {
    float l = decf(bbox[b*6+a]), h = decf(bbox[b*6+3+a]);
    float ex = (h - l)*(1.f + 4e-7f) + 1e-30f;
    float inv = (float)HB/ex;
    int bin = (int)((cb[n*3+a] - l)*inv);
    bin = min(HB-1, max(0, bin));
    atomicAdd(&hist[(b*3+a)*HB + bin], 1);
  }
}

// ---------------- equal-frequency edges from histogram cdf ----------------
__global__ void k_edges(const int* __restrict__ hist, const unsigned int* __restrict__ bbox,
                        float* __restrict__ edges) {
  __shared__ int part[256];
  int p = blockIdx.x;                 // pair = b*3 + a, 6 blocks
  int b = p/3, a = p - b*3;
  int tid = threadIdx.x;
  const int* h = hist + p*HB;
  int v[8]; int s = 0;
#pragma unroll
  for (int i = 0; i < 8; ++i) { v[i] = h[tid*8 + i]; s += v[i]; }
  part[tid] = s;
  __syncthreads();
  for (int off = 1; off < 256; off <<= 1) {
    int x = part[tid];
    int y = (tid >= off) ? part[tid-off] : 0;
    __syncthreads();
    part[tid] = x + y;
    __syncthreads();
  }
  float l = decf(bbox[b*6+a]), hi = decf(bbox[b*6+3+a]);
  float ex = (hi - l)*(1.f + 4e-7f) + 1e-30f;
  float bw = ex*(1.f/(float)HB);
  int c = part[tid] - s;              // exclusive base
#pragma unroll
  for (int i = 0; i < 8; ++i) {
    int lo_c = c; c += v[i];
#pragma unroll
    for (int g = 1; g < G; ++g) {
      int tq = g*(NPTS/G);
      if (lo_c < tq && c >= tq) edges[p*(G+1) + g] = l + bw*(float)(tid*8 + i + 1);
    }
  }
  if (tid == 0) { edges[p*(G+1)] = l; edges[p*(G+1) + G] = hi + fabsf(hi)*1e-6f + 1e-20f; }
}

// ---------------- bin points into quantile cells ----------------
__global__ void k_bin(const float* __restrict__ coords, const float* __restrict__ edges,
                      int* __restrict__ cellid, int* __restrict__ gcnt) {
  __shared__ float se[3][G+1];
  int tid = threadIdx.x;
  int t = blockIdx.x*256 + tid;
  int b = t >> 15, n = t & (NPTS-1);
  if (tid < 3*(G+1)) se[tid/(G+1)][tid%(G+1)] = edges[b*3*(G+1) + tid];
  __syncthreads();
  const float* cb = coords + (size_t)b*(NPTS*3);
  int c0 = bs16(se[0], cb[n*3+0]);
  int c1 = bs16(se[1], cb[n*3+1]);
  int c2 = bs16(se[2], cb[n*3+2]);
  int cid = b*G3 + (c2*G + c1)*G + c0;
  cellid[t] = cid;
  atomicAdd(&gcnt[cid], 1);
}

// ---------------- deterministic global scan over all 8192 cells ----------------
__global__ void k_alloc(const int* __restrict__ gcnt, int* __restrict__ gstart,
                        int* __restrict__ starts) {
  __shared__ int part[1024];
  int tid = threadIdx.x;
  int v[8]; int s = 0;
#pragma unroll
  for (int i = 0; i < 8; ++i) { v[i] = gcnt[tid*8 + i]; s += v[i]; }
  part[tid] = s;
  __syncthreads();
  for (int off = 1; off < 1024; off <<= 1) {
    int x = part[tid];
    int y = (tid >= off) ? part[tid-off] : 0;
    __syncthreads();
    part[tid] = x + y;
    __syncthreads();
  }
  int base = part[tid] - s;
#pragma unroll
  for (int i = 0; i < 8; ++i) { gstart[tid*8 + i] = base; starts[tid*8 + i] = base; base += v[i]; }
  if (tid == 1023) starts[2*G3] = NQ;
}

// ---------------- scatter: packed float4 + original id, cell-sorted ----------------
__global__ void k_scatter(const float* __restrict__ coords, const int* __restrict__ cellid,
                          int* __restrict__ gstart, float4* __restrict__ csort,
                          int* __restrict__ sortid) {
  int t = blockIdx.x*256 + threadIdx.x;
  int b = t >> 15, n = t & (NPTS-1);
  const float* cb = coords + (size_t)b*(NPTS*3);
  int cid = cellid[t];
  int pos = atomicAdd(&gstart[cid], 1);
  float x = cb[n*3+0], y = cb[n*3+1], z = cb[n*3+2];
  csort[pos] = make_float4(x, y, z, x*x + y*y + z*z);
  sortid[pos] = n;
}

// ---------------- cell-centric KNN: one block per cell, 3x3x3 region in LDS ----------------
__launch_bounds__(256)
__global__ void k_cellknn(const float4* __restrict__ csort, const int* __restrict__ sortid,
                          const int* __restrict__ starts, const float* __restrict__ edges,
                          int* __restrict__ oidx, int* __restrict__ faillist,
                          int* __restrict__ failcnt) {
  __shared__ float4 cand[CAPC];       // 8 KB
  __shared__ int    cid[CAPC];        // 2 KB
  __shared__ float  sdist[4][CAPC];   // 8 KB
  __shared__ int    rs[9], rl[9], pre[10];
  int tid = threadIdx.x, lane = tid & 63, w = tid >> 6;
  int blk = blockIdx.x;
  int b = blk >> 12;                  // G3 = 4096 cells per batch
  int c = blk & (G3-1);
  int cxi = c & 15, cyi = (c >> 4) & 15, czi = c >> 8;
  const int* st = starts + b*G3;
  if (tid < 9) {
    int dz = tid/3 - 1, dy = tid%3 - 1;
    int z = czi + dz, y = cyi + dy;
    if (z < 0 || z > G-1 || y < 0 || y > G-1) { rs[tid] = 0; rl[tid] = 0; }
    else {
      int xa = max(cxi-1, 0), xb = min(cxi+1, G-1);
      int c0 = (z*G + y)*G + xa;
      int s0 = st[c0], e0 = st[c0 + (xb - xa) + 1];
      rs[tid] = s0; rl[tid] = e0 - s0;
    }
  }
  __syncthreads();
  if (tid == 0) {
    int acc = 0;
#pragma unroll
    for (int i = 0; i < 9; ++i) { pre[i] = acc; acc += rl[i]; }
    pre[9] = acc;
  }
  __syncthreads();
  int total = pre[9];
  int hs = st[c], he = st[c+1];
  int nq = he - hs;
  if (nq == 0) return;                           // uniform across block
  bool bad = (total > CAPC) || (total < KK);
  if (!bad) {
    for (int i = tid; i < total; i += 256) {
      int row = 0;
#pragma unroll
      for (int rr = 1; rr < 9; ++rr) row += (i >= pre[rr]);
      int gp = rs[row] + (i - pre[row]);
      cand[i] = csort[gp];
      cid[i]  = sortid[gp];
    }
  }
  __syncthreads();
  int hoff = pre[4] + (hs - rs[4]);              // home cell offset inside cand[]
  // region boundary edge positions (skip sides clipped at the grid border)
  float blo[3], bhi[3]; bool blok[3], bhik[3];
  int cc3[3] = {cxi, cyi, czi};
#pragma unroll
  for (int a = 0; a < 3; ++a) {
    const float* e = edges + (b*3 + a)*(G+1);
    blok[a] = cc3[a] > 0;     blo[a] = blok[a] ? e[cc3[a]-1] : 0.f;
    bhik[a] = cc3[a] < G-1;   bhi[a] = bhik[a] ? e[cc3[a]+2] : 0.f;
  }
  for (int q0 = 0; q0 < nq; q0 += 4) {
    int qi = q0 + w;
    if (qi >= nq) continue;                      // uniform per wave
    int t = hs + qi;                             // query = csort position
    if (bad) {
      if (lane == 0) { int pos = atomicAdd(failcnt, 1); faillist[pos] = t; }
      continue;
    }
    float4 qv = cand[hoff + qi];
    float qx = qv.x, qy = qv.y, qz = qv.z, qsq = qv.w;
    for (int i = lane; i < total; i += 64) {
      float4 p = cand[i];
      sdist[w][i] = qsq + p.w - 2.f*(qx*p.x + qy*p.y + qz*p.z);  // == reference formula
    }
    int res = 0; float d16v = 0.f;
#pragma unroll
    for (int r = 0; r < KK; ++r) {               // 16 exact extraction rounds
      float lm = 1e30f; int ls2 = 0x7fffffff;
      for (int i = lane; i < total; i += 64) {
        float v = sdist[w][i];
        bool bet = (v < lm) || (v == lm && i < ls2);
        lm = bet ? v : lm; ls2 = bet ? i : ls2;
      }
#pragma unroll
      for (int m = 1; m < 64; m <<= 1) {
        float ov = __shfl_xor(lm, m, 64);
        int   os = __shfl_xor(ls2, m, 64);
        bool bet = (ov < lm) || (ov == lm && os < ls2);
        lm = bet ? ov : lm; ls2 = bet ? os : ls2;
      }
      if (lane == r) res = ls2;
      d16v = lm;                                 // after last round = 16th smallest
      if (lane == 0) sdist[w][ls2] = 1e30f;      // pop winner (wave-coherent LDS)
    }
    // exactness: ball of radius sqrt(d16v) must lie inside the (clipped) region
    float m = 1e30f;
    if (blok[0]) m = fminf(m, qx - blo[0]);
    if (bhik[0]) m = fminf(m, bhi[0] - qx);
    if (blok[1]) m = fminf(m, qy - blo[1]);
    if (bhik[1]) m = fminf(m, bhi[1] - qy);
    if (blok[2]) m = fminf(m, qz - blo[2]);
    if (bhik[2]) m = fminf(m, bhi[2] - qz);
    bool ok = (m > 0.f) && (m*m > d16v + SLOP);
    if (ok) {
      int qn = cid[hoff + qi];
      size_t row = ((size_t)(b*NPTS + qn))*KK;
      if (lane < KK) oidx[row + lane] = cid[res];
    } else {
      if (lane == 0) { int pos = atomicAdd(failcnt, 1); faillist[pos] = t; }
    }
  }
}

// ---------------- fallback: exact one-wave-per-query shell walk (round-6 proven) ----------------
__launch_bounds__(256)
__global__ void k_knn_fb(const float4* __restrict__ csort, const int* __restrict__ sortid,
                         const int* __restrict__ starts, const float* __restrict__ edges,
                         const int* __restrict__ faillist, const int* __restrict__ failcnt,
                         int* __restrict__ oidx) {
  int lane = threadIdx.x & 63;
  int gw = (blockIdx.x*256 + threadIdx.x) >> 6;
  int nw = (gridDim.x*256) >> 6;
  int nf = failcnt[0];
  for (int f = gw; f < nf; f += nw) {
    int t = faillist[f];
    int b = t >> 15;
    const int* st = starts + b*G3;
    const float* ex = edges + (b*3+0)*(G+1);
    const float* ey = edges + (b*3+1)*(G+1);
    const float* ez = edges + (b*3+2)*(G+1);
    float4 qv = csort[t];
    const float qx = qv.x, qy = qv.y, qz = qv.z, qsq = qv.w;
    const int cx = bs16(ex, qx), cy = bs16(ey, qy), cz = bs16(ez, qz);
    float dl[KK]; int il[KK];
#pragma unroll
    for (int i = 0; i < KK; ++i) { dl[i] = 1e30f; il[i] = 0; }
    auto prange = [&](int s0, int e0) {
      for (int i = s0 + lane; i < e0; i += 64) {
        float4 p = csort[i];
        float d = qsq + p.w - 2.f*(qx*p.x + qy*p.y + qz*p.z);
        if (d < dl[KK-1]) {
          float cd = d; int ci = i;
#pragma unroll
          for (int i2 = 0; i2 < KK; ++i2) {
            bool sw = cd < dl[i2];
            float td = dl[i2]; int ti = il[i2];
            dl[i2] = sw ? cd : td; il[i2] = sw ? ci : ti;
            cd = sw ? td : cd;    ci = sw ? ti : ci;
          }
        }
      }
    };
    auto prow = [&](int y, int z, int xa, int xb) {
      int c0 = (z*G + y)*G + xa;
      prange(st[c0], st[c0 + (xb - xa) + 1]);
    };
    for (int r = 0; r <= G; ++r) {
      if (r >= 1) {
        int rm = r - 1;
        if (cx-rm <= 0 && cx+rm >= G-1 && cy-rm <= 0 && cy+rm >= G-1 &&
            cz-rm <= 0 && cz+rm >= G-1) break;
        float v = dl[0];
#pragma unroll
        for (int k2 = 2; k2 <= 64; k2 <<= 1) {
#pragma unroll
          for (int j = k2 >> 1; j > 0; j >>= 1) {
            float o = __shfl_xor(v, j, 64);
            bool keepmin = (((lane & j) == 0) == ((lane & k2) == 0));
            v = keepmin ? fminf(v, o) : fmaxf(v, o);
          }
        }
        float bound = __shfl(v, 15, 64);
        if (bound < 1e29f) {
          float m = 1e30f;
          if (cx-rm > 0)   m = fminf(m, qx - ex[cx-rm]);
          if (cx+rm < G-1) m = fminf(m, ex[cx+rm+1] - qx);
          if (cy-rm > 0)   m = fminf(m, qy - ey[cy-rm]);
          if (cy+rm < G-1) m = fminf(m, ey[cy+rm+1] - qy);
          if (cz-rm > 0)   m = fminf(m, qz - ez[cz-rm]);
          if (cz+rm < G-1) m = fminf(m, ez[cz+rm+1] - qz);
          if (m > 0.f && m*m > bound + SLOP) break;
        }
      }
      int zlo = max(cz-r, 0), zhi = min(cz+r, G-1);
      for (int z = zlo; z <= zhi; ++z) {
        bool zf = (z == cz-r) || (z == cz+r);
        int ylo = max(cy-r, 0), yhi = min(cy+r, G-1);
        for (int y = ylo; y <= yhi; ++y) {
          bool yf = (y == cy-r) || (y == cy+r);
          if (zf || yf) {
            prow(y, z, max(cx-r, 0), min(cx+r, G-1));
          } else {
            if (cx-r >= 0)   prow(y, z, cx-r, cx-r);
            if (cx+r <= G-1) prow(y, z, cx+r, cx+r);
          }
        }
      }
    }
    int res = 0;
#pragma unroll
    for (int r = 0; r < KK; ++r) {
      float v = dl[0]; int l = lane;
#pragma unroll
      for (int m = 1; m < 64; m <<= 1) {
        float ov = __shfl_xor(v, m, 64);
        int   ol = __shfl_xor(l, m, 64);
        bool take = (ov < v) || (ov == v && ol < l);
        v = take ? ov : v;
        l = take ? ol : l;
      }
      int wi = __shfl(il[0], l, 64);
      if (lane == r) res = wi;
      bool win = (lane == l);
#pragma unroll
      for (int i = 0; i < KK-1; ++i) {
        dl[i] = win ? dl[i+1] : dl[i];
        il[i] = win ? il[i+1] : il[i];
      }
      dl[KK-1] = win ? 1e30f : dl[KK-1];
    }
    int qn = sortid[t];
    size_t row = ((size_t)(b*NPTS + qn))*KK;
    if (lane < KK) oidx[row + lane] = sortid[res];
  }
}

// ---------------- mlp1 (leaky 0.2) + shortcut BN stats ----------------
__global__ void k_mlp1(const float* __restrict__ features,
                       const float* __restrict__ W1, const float* __restrict__ b1,
                       const float* __restrict__ Wsc, const float* __restrict__ bsc,
                       float* __restrict__ x1, float* __restrict__ stats) {
  __shared__ float sW1[128], sb1[16], sWsc[512], sbsc[64];
  int tid = threadIdx.x;
  if (tid < 128) sW1[tid] = W1[tid];
  if (tid < 16)  sb1[tid] = b1[tid];
  if (tid < 64)  sbsc[tid] = bsc[tid];
  for (int i = tid; i < 512; i += 256) sWsc[i] = Wsc[i];
  __syncthreads();
  int q = blockIdx.x*256 + tid;
  int b = q >> 15, n = q & (NPTS-1);
  float f[8];
#pragma unroll
  for (int c = 0; c < 8; ++c) f[c] = features[((size_t)b*8 + c)*NPTS + n];
#pragma unroll
  for (int co = 0; co < 16; ++co) {
    float a = sb1[co];
#pragma unroll
    for (int c = 0; c < 8; ++c) a += f[c]*sW1[co*8+c];
    x1[(size_t)q*16 + co] = a > 0.f ? a : 0.2f*a;
  }
  int lane = tid & 63;
#pragma unroll
  for (int co = 0; co < 64; ++co) {
    float a = sbsc[co];
#pragma unroll
    for (int c = 0; c < 8; ++c) a += f[c]*sWsc[co*8+c];
    float s = wred64(a), ss = wred64(a*a);
    if (lane == 0) { atomicAdd(&stats[S_SC+co], s); atomicAdd(&stats[S_SC+64+co], ss); }
  }
}

// ---------------- BN stats for BOTH LSE geometric encodings ----------------
__global__ void k_lsestats(const float* __restrict__ coords, const int* __restrict__ idx,
                           const float* __restrict__ Wl1, const float* __restrict__ bl1,
                           const float* __restrict__ Wl2, const float* __restrict__ bl2,
                           float* __restrict__ stats) {
  __shared__ float sW1[160], sb1[16], sW2[160], sb2[16];
  __shared__ float red[4][64];
  int tid = threadIdx.x;
  for (int i = tid; i < 160; i += 256) { sW1[i] = Wl1[i]; sW2[i] = Wl2[i]; }
  if (tid < 16) { sb1[tid] = bl1[tid]; sb2[tid] = bl2[tid]; }
  __syncthreads();
  int t = blockIdx.x*256 + tid;         // (b,n,k) flat
  int q = t >> 4;
  int b = q >> 15, n = q & (NPTS-1);
  const float* cb = coords + (size_t)b*(NPTS*3);
  int j = idx[t];
  float cx = cb[n*3], cy = cb[n*3+1], cz = cb[n*3+2];
  float px = cb[j*3], py = cb[j*3+1], pz = cb[j*3+2];
  float cat[10] = {cx,cy,cz,px,py,pz,cx-px,cy-py,cz-pz,1.f};
  int wave = tid >> 6, lane = tid & 63;
#pragma unroll
  for (int co = 0; co < 16; ++co) {
    float a1 = sb1[co], a2 = sb2[co];
#pragma unroll
    for (int d0 = 0; d0 < 10; ++d0) { a1 += cat[d0]*sW1[co*10+d0]; a2 += cat[d0]*sW2[co*10+d0]; }
    float s1 = wred64(a1), q1 = wred64(a1*a1);
    float s2 = wred64(a2), q2 = wred64(a2*a2);
    if (lane == 0) { red[wave][co]=s1; red[wave][16+co]=q1; red[wave][32+co]=s2; red[wave][48+co]=q2; }
  }
  __syncthreads();
  if (tid < 64) {
    float v = red[0][tid] + red[1][tid] + red[2][tid] + red[3][tid];
    int grp = tid >> 4, c = tid & 15;
    int off = (grp == 0) ? (S_L1 + c) : (grp == 1) ? (S_L1 + 16 + c)
            : (grp == 2) ? (S_L2 + c) : (S_L2 + 16 + c);
    atomicAdd(&stats[off], v);
  }
}

// ---------------- BN finalize ----------------
__global__ void k_bnfin(const float* __restrict__ stats, float* __restrict__ coef,
                        const float* __restrict__ gam, const float* __restrict__ bet,
                        int soff, int coff, int nch, float invc) {
  int c = threadIdx.x;
  if (c < nch) {
    float m = stats[soff + c]*invc;
    float v = stats[soff + nch + c]*invc - m*m;
    float a = gam[c]*rsqrtf(v + EPS);
    coef[coff + c] = a;
    coef[coff + nch + c] = bet[c] - m*a;
  }
}

// ---------------- LSE1 + attentive pooling 1 ----------------
__launch_bounds__(256)
__global__ void k_att1(const float* __restrict__ coords, const int* __restrict__ idx,
                       const float* __restrict__ x1ws,
                       const float* __restrict__ Wl1, const float* __restrict__ bl1,
                       const float* __restrict__ Ws1, const float* __restrict__ Wp1,
                       const float* __restrict__ bp1, const float* __restrict__ coef,
                       float* __restrict__ t2, float* __restrict__ stats) {
  __shared__ float sWl[160], sbl[16];
  __shared__ float sWs[1024];
  __shared__ float sWpT[512], sbp[16];
  __shared__ float lsum[16], lsq[16];
  int tid = threadIdx.x;
  for (int i = tid; i < 160; i += 256) { int c = i/10; sWl[i] = Wl1[i]*coef[C_L1 + c]; }
  if (tid < 16) sbl[tid] = bl1[tid]*coef[C_L1+tid] + coef[C_L1+16+tid];
  for (int i = tid; i < 1024; i += 256) sWs[i] = Ws1[i];
  for (int i = tid; i < 512; i += 256) { int co = i >> 4, cp = i & 15; sWpT[i] = Wp1[cp*32 + co]; }
  if (tid < 16) { sbp[tid] = bp1[tid]; lsum[tid] = 0.f; lsq[tid] = 0.f; }
  __syncthreads();
  int gp = blockIdx.x*16 + (tid >> 4);
  int k  = tid & 15;
  int b = gp >> 15, n = gp & (NPTS-1);
  const float* cb = coords + (size_t)b*(NPTS*3);
  int j = idx[(size_t)gp*KK + k];
  float cx = cb[n*3], cy = cb[n*3+1], cz = cb[n*3+2];
  float px = cb[j*3], py = cb[j*3+1], pz = cb[j*3+2];
  float cat[10] = {cx,cy,cz,px,py,pz,cx-px,cy-py,cz-pz,1.f};
  float x[32];
#pragma unroll
  for (int co = 0; co < 16; ++co) {
    float a = sbl[co];
#pragma unroll
    for (int d0 = 0; d0 < 10; ++d0) a += cat[d0]*sWl[co*10+d0];
    x[co] = a > 0.f ? a : 0.f;
  }
  {
    const float4* xp = (const float4*)(x1ws + (size_t)gp*16);
    float4 u0 = xp[0], u1 = xp[1], u2 = xp[2], u3 = xp[3];
    x[16]=u0.x; x[17]=u0.y; x[18]=u0.z; x[19]=u0.w;
    x[20]=u1.x; x[21]=u1.y; x[22]=u1.z; x[23]=u1.w;
    x[24]=u2.x; x[25]=u2.y; x[26]=u2.z; x[27]=u2.w;
    x[28]=u3.x; x[29]=u3.y; x[30]=u3.z; x[31]=u3.w;
  }
  float tacc = sbp[k];
#pragma unroll
  for (int co = 0; co < 32; ++co) {
    float s = 0.f;
#pragma unroll
    for (int ci = 0; ci < 32; ++ci) s += x[ci]*sWs[co*32+ci];
    float m = s;
#pragma unroll
    for (int msk = 8; msk > 0; msk >>= 1) m = fmaxf(m, __shfl_xor(m, msk, 16));
    float e = __expf(s - m);
    float se = e;
#pragma unroll
    for (int msk = 8; msk > 0; msk >>= 1) se += __shfl_xor(se, msk, 16);
    float w = e/se;
    float fv = w*x[co];
#pragma unroll
    for (int msk = 8; msk > 0; msk >>= 1) fv += __shfl_xor(fv, msk, 16);
    tacc += fv*sWpT[co*16+k];
  }
  t2[(size_t)gp*16 + k] = tacc;
  atomicAdd(&lsum[k], tacc);
  atomicAdd(&lsq[k], tacc*tacc);
  __syncthreads();
  if (tid < 16) { atomicAdd(&stats[S_P1+tid], lsum[tid]); atomicAdd(&stats[S_P1+16+tid], lsq[tid]); }
}

// ---------------- LSE2 + attentive pooling 2 ----------------
__launch_bounds__(256)
__global__ void k_att2(const float* __restrict__ coords, const int* __restrict__ idx,
                       const float* __restrict__ t2ws,
                       const float* __restrict__ Wl2, const float* __restrict__ bl2,
                       const float* __restrict__ Ws2, const float* __restrict__ Wp2,
                       const float* __restrict__ bp2, const float* __restrict__ coef,
                       float* __restrict__ t4, float* __restrict__ stats) {
  __shared__ float sWl[160], sbl[16];
  __shared__ float sWs[1024];
  __shared__ float sWpT[1024], sbp[32];
  __shared__ float sa1[16], sc1[16];
  __shared__ float lsum[32], lsq[32];
  int tid = threadIdx.x;
  for (int i = tid; i < 160; i += 256) { int c = i/10; sWl[i] = Wl2[i]*coef[C_L2 + c]; }
  if (tid < 16) sbl[tid] = bl2[tid]*coef[C_L2+tid] + coef[C_L2+16+tid];
  for (int i = tid; i < 1024; i += 256) {
    sWs[i] = Ws2[i];
    int co = i >> 5, cp = i & 31; sWpT[i] = Wp2[cp*32 + co];
  }
  if (tid < 32) { sbp[tid] = bp2[tid]; lsum[tid]=0.f; lsq[tid]=0.f; }
  if (tid < 16) { sa1[tid] = coef[C_P1+tid]; sc1[tid] = coef[C_P1+16+tid]; }
  __syncthreads();
  int gp = blockIdx.x*16 + (tid >> 4);
  int k  = tid & 15;
  int b = gp >> 15, n = gp & (NPTS-1);
  const float* cb = coords + (size_t)b*(NPTS*3);
  int j = idx[(size_t)gp*KK + k];
  float cx = cb[n*3], cy = cb[n*3+1], cz = cb[n*3+2];
  float px = cb[j*3], py = cb[j*3+1], pz = cb[j*3+2];
  float cat[10] = {cx,cy,cz,px,py,pz,cx-px,cy-py,cz-pz,1.f};
  float x[32];
#pragma unroll
  for (int co = 0; co < 16; ++co) {
    float a = sbl[co];
#pragma unroll
    for (int d0 = 0; d0 < 10; ++d0) a += cat[d0]*sWl[co*10+d0];
    x[co] = a > 0.f ? a : 0.f;
  }
  {
    const float4* xp = (const float4*)(t2ws + (size_t)gp*16);
    float4 u0 = xp[0], u1 = xp[1], u2 = xp[2], u3 = xp[3];
    float xv[16] = {u0.x,u0.y,u0.z,u0.w, u1.x,u1.y,u1.z,u1.w,
                    u2.x,u2.y,u2.z,u2.w, u3.x,u3.y,u3.z,u3.w};
#pragma unroll
    for (int c = 0; c < 16; ++c) {
      float v = xv[c]*sa1[c] + sc1[c];
      x[16+c] = v > 0.f ? v : 0.f;
    }
  }
  float tacc0 = sbp[k], tacc1 = sbp[k+16];
#pragma unroll
  for (int co = 0; co < 32; ++co) {
    float s = 0.f;
#pragma unroll
    for (int ci = 0; ci < 32; ++ci) s += x[ci]*sWs[co*32+ci];
    float m = s;
#pragma unroll
    for (int msk = 8; msk > 0; msk >>= 1) m = fmaxf(m, __shfl_xor(m, msk, 16));
    float e = __expf(s - m);
    float se = e;
#pragma unroll
    for (int msk = 8; msk > 0; msk >>= 1) se += __shfl_xor(se, msk, 16);
    float w = e/se;
    float fv = w*x[co];
#pragma unroll
    for (int msk = 8; msk > 0; msk >>= 1) fv += __shfl_xor(fv, msk, 16);
    tacc0 += fv*sWpT[co*32+k];
    tacc1 += fv*sWpT[co*32+k+16];
  }
  t4[(size_t)gp*32 + k]      = tacc0;
  t4[(size_t)gp*32 + k + 16] = tacc1;
  atomicAdd(&lsum[k], tacc0);      atomicAdd(&lsq[k], tacc0*tacc0);
  atomicAdd(&lsum[k+16], tacc1);   atomicAdd(&lsq[k+16], tacc1*tacc1);
  __syncthreads();
  if (tid < 32) { atomicAdd(&stats[S_P2+tid], lsum[tid]); atomicAdd(&stats[S_P2+32+tid], lsq[tid]); }
}

// ---------------- final: mlp2 + BN'd shortcut + leaky 0.01 ----------------
__global__ void k_final(const float* __restrict__ t4ws, const float* __restrict__ features,
                        const float* __restrict__ W2, const float* __restrict__ b2,
                        const float* __restrict__ Wsc, const float* __restrict__ bsc,
                        const float* __restrict__ coef, float* __restrict__ out) {
  __shared__ float sW2[2048], sb2[64], sWscF[512], sbscF[64], sa[32], scc[32];
  int tid = threadIdx.x;
  for (int i = tid; i < 2048; i += 256) sW2[i] = W2[i];
  if (tid < 64) sb2[tid] = b2[tid];
  for (int i = tid; i < 512; i += 256) { int c2 = i >> 3; sWscF[i] = Wsc[i]*coef[C_SC + c2]; }
  if (tid < 64) sbscF[tid] = bsc[tid]*coef[C_SC+tid] + coef[C_SC+64+tid];
  if (tid < 32) { sa[tid] = coef[C_P2+tid]; scc[tid] = coef[C_P2+32+tid]; }
  __syncthreads();
  int q = blockIdx.x*256 + tid;
  int b = q >> 15, n = q & (NPTS-1);
  float x3[32];
  const float4* tp = (const float4*)(t4ws + (size_t)q*32);
#pragma unroll
  for (int i = 0; i < 8; ++i) {
    float4 u = tp[i];
    float v0 = u.x*sa[4*i+0] + scc[4*i+0];
    float v1 = u.y*sa[4*i+1] + scc[4*i+1];
    float v2 = u.z*sa[4*i+2] + scc[4*i+2];
    float v3 = u.w*sa[4*i+3] + scc[4*i+3];
    x3[4*i+0] = v0 > 0.f ? v0 : 0.f;
    x3[4*i+1] = v1 > 0.f ? v1 : 0.f;
    x3[4*i+2] = v2 > 0.f ? v2 : 0.f;
    x3[4*i+3] = v3 > 0.f ? v3 : 0.f;
  }
  float f[8];
#pragma unroll
  for (int c = 0; c < 8; ++c) f[c] = features[((size_t)b*8+c)*NPTS + n];
  for (int c2 = 0; c2 < 64; ++c2) {
    float acc = sb2[c2];
#pragma unroll
    for (int co = 0; co < 32; ++co) acc += x3[co]*sW2[c2*32+co];
    float sv = sbscF[c2];
#pragma unroll
    for (int c = 0; c < 8; ++c) sv += f[c]*sWscF[c2*8+c];
    float o = acc + sv;
    out[((size_t)b*64 + c2)*NPTS + n] = o > 0.f ? o : 0.01f*o;
  }
}

extern "C" void kernel_launch(void* const* d_in, const int* in_sizes, int n_in,
                              void* d_out, int out_size, void* d_ws, size_t ws_size,
                              hipStream_t stream) {
  const float* coords   = (const float*)d_in[0];
  const float* features = (const float*)d_in[1];
  const float* W1  = (const float*)d_in[2];
  const float* b1  = (const float*)d_in[3];
  const float* Wl1 = (const float*)d_in[4];
  const float* bl1 = (const float*)d_in[5];
  const float* gl1 = (const float*)d_in[6];
  const float* bl1b= (const float*)d_in[7];
  const float* Ws1 = (const float*)d_in[8];
  const float* Wp1 = (const float*)d_in[9];
  const float* bp1 = (const float*)d_in[10];
  const float* gp1 = (const float*)d_in[11];
  const float* bp1b= (const float*)d_in[12];
  const float* Wl2 = (const float*)d_in[13];
  const float* bl2 = (const float*)d_in[14];
  const float* gl2 = (const float*)d_in[15];
  const float* bl2b= (const float*)d_in[16];
  const float* Ws2 = (const float*)d_in[17];
  const float* Wp2 = (const float*)d_in[18];
  const float* bp2 = (const float*)d_in[19];
  const float* gp2 = (const float*)d_in[20];
  const float* bp2b= (const float*)d_in[21];
  const float* W2  = (const float*)d_in[22];
  const float* b2  = (const float*)d_in[23];
  const float* Wsc = (const float*)d_in[24];
  const float* bsc = (const float*)d_in[25];
  const float* gsc = (const float*)d_in[26];
  const float* bscb= (const float*)d_in[27];

  float* wsF  = (float*)d_ws;
  int*   wsI  = (int*)d_ws;
  int*   idxp = wsI;
  float* x1p  = wsF + WS_X1;
  float* t2p  = wsF + WS_T2;
  float* t4p  = wsF + WS_T4;
  float* stat = wsF + WS_STAT;
  float* coef = wsF + WS_COEF;
  int*   gcnt = wsI + WS_GCNT;
  int*   gsta = wsI + WS_GSTART;
  int*   gcel = wsI + WS_CELLID;
  int*   sid  = wsI + WS_SORTID;
  float4* csrt = (float4*)(wsF + WS_CSORT);
  unsigned int* bbox = (unsigned int*)(wsI + WS_BBOX);
  int*   fcnt = wsI + WS_BBOX + 12;       // within bbox's 16-slot region
  int*   flist= wsI + WS_FAIL;            // aliases cellid (dead after scatter)
  int*   hist = wsI + WS_HIST;
  int*   strt = wsI + WS_STARTS;          // aliases hist (dead after k_edges)
  float* edge = wsF + WS_EDGE;
  float* outp = (float*)d_out;

  hipLaunchKernelGGL(k_zero_all, dim3(48), dim3(256), 0, stream, stat, gcnt, hist, bbox, fcnt);
  hipLaunchKernelGGL(k_bbox,    dim3(NQ/256), dim3(256), 0, stream, coords, bbox);
  hipLaunchKernelGGL(k_hist,    dim3(NQ/256), dim3(256), 0, stream, coords, bbox, hist);
  hipLaunchKernelGGL(k_edges,   dim3(6), dim3(256), 0, stream, hist, bbox, edge);
  hipLaunchKernelGGL(k_bin,     dim3(NQ/256), dim3(256), 0, stream, coords, edge, gcel, gcnt);
  hipLaunchKernelGGL(k_alloc,   dim3(1), dim3(1024), 0, stream, gcnt, gsta, strt);
  hipLaunchKernelGGL(k_scatter, dim3(NQ/256), dim3(256), 0, stream, coords, gcel, gsta, csrt, sid);
  hipLaunchKernelGGL(k_cellknn, dim3(2*G3), dim3(256), 0, stream,
                     csrt, sid, strt, edge, idxp, flist, fcnt);
  hipLaunchKernelGGL(k_knn_fb,  dim3(1024), dim3(256), 0, stream,
                     csrt, sid, strt, edge, flist, fcnt, idxp);
  hipLaunchKernelGGL(k_mlp1, dim3(NQ/256), dim3(256), 0, stream,
                     features, W1, b1, Wsc, bsc, x1p, stat);
  hipLaunchKernelGGL(k_lsestats, dim3((NQ*KK)/256), dim3(256), 0, stream,
                     coords, idxp, Wl1, bl1, Wl2, bl2, stat);
  hipLaunchKernelGGL(k_bnfin, dim3(1), dim3(64), 0, stream, stat, coef, gl1, bl1b,
                     S_L1, C_L1, 16, 1.f/(float)((size_t)NQ*KK));
  hipLaunchKernelGGL(k_bnfin, dim3(1), dim3(64), 0, stream, stat, coef, gl2, bl2b,
                     S_L2, C_L2, 16, 1.f/(float)((size_t)NQ*KK));
  hipLaunchKernelGGL(k_bnfin, dim3(1), dim3(64), 0, stream, stat, coef, gsc, bscb,
                     S_SC, C_SC, 64, 1.f/(float)NQ);
  hipLaunchKernelGGL(k_att1, dim3(NQ/16), dim3(256), 0, stream,
                     coords, idxp, x1p, Wl1, bl1, Ws1, Wp1, bp1, coef, t2p, stat);
  hipLaunchKernelGGL(k_bnfin, dim3(1), dim3(64), 0, stream, stat, coef, gp1, bp1b,
                     S_P1, C_P1, 16, 1.f/(float)NQ);
  hipLaunchKernelGGL(k_att2, dim3(NQ/16), dim3(256), 0, stream,
                     coords, idxp, t2p, Wl2, bl2, Ws2, Wp2, bp2, coef, t4p, stat);
  hipLaunchKernelGGL(k_bnfin, dim3(1), dim3(64), 0, stream, stat, coef, gp2, bp2b,
                     S_P2, C_P2, 32, 1.f/(float)NQ);
  hipLaunchKernelGGL(k_final, dim3(NQ/256), dim3(256), 0, stream,
                     t4p, features, W2, b2, Wsc, bsc, coef, outp);
}

// Round 9
// 1980.313 us; speedup vs baseline: 2.1766x; 1.1992x over previous
//
#include <hip/hip_runtime.h>
#include <math.h>

#define NPTS  32768
#define NB    2
#define NQ    (NB*NPTS)
#define KK    16
#define EPS   1e-6f
#define G     16
#define G3    (G*G*G)
#define HB    2048
#define SLOP  0.05f
#define CAPC  512

// stats / coef element offsets
#define S_L1 0
#define S_L2 32
#define S_P1 64
#define S_P2 96
#define S_SC 160
#define C_L1 0
#define C_L2 32
#define C_P1 64
#define C_P2 96
#define C_SC 160

// workspace element offsets (4-byte units)
#define WS_X1     (NQ*16)
#define WS_T2     (NQ*32)
#define WS_T4     (NQ*48)
#define WS_STAT   (NQ*80)
#define WS_COEF   (WS_STAT + 512)
#define WS_GCNT   (WS_STAT + 1024)
#define WS_GSTART (WS_GCNT + 2*G3)
#define WS_CELLID (WS_GSTART + 2*G3)
#define WS_SORTID (WS_CELLID + NQ)
#define WS_CSORT  (WS_SORTID + NQ)      /* float4 x NQ (16B-aligned) */
#define WS_BBOX   (WS_CSORT + 4*NQ)
#define WS_HIST   (WS_BBOX + 16)
#define WS_EDGE   (WS_HIST + 6*HB)
#define WS_STARTS WS_HIST               /* starts aliases hist (dead after k_edges) */
#define WS_FAIL   WS_CELLID             /* fail list aliases cellid (dead after scatter) */

#define FB_BAD    (1 << 30)             /* faillist tag: bad cell -> unseeded full walk */

__device__ __forceinline__ float wred64(float v) {
#pragma unroll
  for (int m = 32; m > 0; m >>= 1) v += __shfl_xor(v, m, 64);
  return v;
}

// order-preserving float <-> uint encoding for atomic min/max
__device__ __forceinline__ unsigned int encf(float f) {
  unsigned int u = __float_as_uint(f);
  return (u & 0x80000000u) ? ~u : (u | 0x80000000u);
}
__device__ __forceinline__ float decf(unsigned int u) {
  return (u & 0x80000000u) ? __uint_as_float(u & 0x7fffffffu) : __uint_as_float(~u);
}

// 4-step binary search over G=16 quantile edges; e[0] <= x guaranteed
__device__ __forceinline__ int bs16(const float* e, float x) {
  int c = (x >= e[8]) ? 8 : 0;
  c += (x >= e[c+4]) ? 4 : 0;
  c += (x >= e[c+2]) ? 2 : 0;
  c += (x >= e[c+1]) ? 1 : 0;
  return c;
}

// ---------------- zero stats + counters + hist + bbox + failcnt ----------------
__global__ void k_zero_all(float* __restrict__ stats, int* __restrict__ gcnt,
                           int* __restrict__ hist, unsigned int* __restrict__ bbox,
                           int* __restrict__ failcnt) {
  int i = blockIdx.x*256 + threadIdx.x;       // grid covers 12288
  if (i < 2*G3) gcnt[i] = 0;
  if (i < 6*HB) hist[i] = 0;
  if (i < 320)  stats[i] = 0.f;
  if (i < 12)   bbox[i] = ((i % 6) < 3) ? 0xFFFFFFFFu : 0u;
  if (i == 0)   failcnt[0] = 0;
}

// ---------------- per-batch exact bounding box ----------------
__global__ void k_bbox(const float* __restrict__ coords, unsigned int* __restrict__ bbox) {
  __shared__ unsigned int rmn[3][4], rmx[3][4];
  int tid = threadIdx.x;
  int t = blockIdx.x*256 + tid;
  int b = t >> 15, n = t & (NPTS-1);
  const float* cb = coords + (size_t)b*(NPTS*3);
  unsigned int e[3] = { encf(cb[n*3+0]), encf(cb[n*3+1]), encf(cb[n*3+2]) };
  unsigned int mn[3] = { e[0], e[1], e[2] }, mx[3] = { e[0], e[1], e[2] };
#pragma unroll
  for (int s = 32; s > 0; s >>= 1) {
#pragma unroll
    for (int a = 0; a < 3; ++a) {
      unsigned int o1 = (unsigned int)__shfl_xor((int)mn[a], s, 64);
      unsigned int o2 = (unsigned int)__shfl_xor((int)mx[a], s, 64);
      mn[a] = mn[a] < o1 ? mn[a] : o1;
      mx[a] = mx[a] > o2 ? mx[a] : o2;
    }
  }
  int wave = tid >> 6, lane = tid & 63;
  if (lane == 0) {
#pragma unroll
    for (int a = 0; a < 3; ++a) { rmn[a][wave] = mn[a]; rmx[a][wave] = mx[a]; }
  }
  __syncthreads();
  if (tid < 3) {
    unsigned int a0 = min(min(rmn[tid][0], rmn[tid][1]), min(rmn[tid][2], rmn[tid][3]));
    unsigned int A0 = max(max(rmx[tid][0], rmx[tid][1]), max(rmx[tid][2], rmx[tid][3]));
    atomicMin(&bbox[b*6 + tid], a0);
    atomicMax(&bbox[b*6 + 3 + tid], A0);
  }
}

// ---------------- per-axis fine histogram ----------------
__global__ void k_hist(const float* __restrict__ coords, const unsigned int* __restrict__ bbox,
                       int* __restrict__ hist) {
  int t = blockIdx.x*256 + threadIdx.x;
  int b = t >> 15, n = t & (NPTS-1);
  const float* cb = coords + (size_t)b*(NPTS*3);
#pragma unroll
  for (int a = 0; a < 3; ++a) {
    float l = decf(bbox[b*6+a]), h = decf(bbox[b*6+3+a]);
    float ex = (h - l)*(1.f + 4e-7f) + 1e-30f;
    float inv = (float)HB/ex;
    int bin = (int)((cb[n*3+a] - l)*inv);
    bin = min(HB-1, max(0, bin));
    atomicAdd(&hist[(b*3+a)*HB + bin], 1);
  }
}

// ---------------- equal-frequency edges from histogram cdf ----------------
__global__ void k_edges(const int* __restrict__ hist, const unsigned int* __restrict__ bbox,
                        float* __restrict__ edges) {
  __shared__ int part[256];
  int p = blockIdx.x;                 // pair = b*3 + a, 6 blocks
  int b = p/3, a = p - b*3;
  int tid = threadIdx.x;
  const int* h = hist + p*HB;
  int v[8]; int s = 0;
#pragma unroll
  for (int i = 0; i < 8; ++i) { v[i] = h[tid*8 + i]; s += v[i]; }
  part[tid] = s;
  __syncthreads();
  for (int off = 1; off < 256; off <<= 1) {
    int x = part[tid];
    int y = (tid >= off) ? part[tid-off] : 0;
    __syncthreads();
    part[tid] = x + y;
    __syncthreads();
  }
  float l = decf(bbox[b*6+a]), hi = decf(bbox[b*6+3+a]);
  float ex = (hi - l)*(1.f + 4e-7f) + 1e-30f;
  float bw = ex*(1.f/(float)HB);
  int c = part[tid] - s;              // exclusive base
#pragma unroll
  for (int i = 0; i < 8; ++i) {
    int lo_c = c; c += v[i];
#pragma unroll
    for (int g = 1; g < G; ++g) {
      int tq = g*(NPTS/G);
      if (lo_c < tq && c >= tq) edges[p*(G+1) + g] = l + bw*(float)(tid*8 + i + 1);
    }
  }
  if (tid == 0) { edges[p*(G+1)] = l; edges[p*(G+1) + G] = hi + fabsf(hi)*1e-6f + 1e-20f; }
}

// ---------------- bin points into quantile cells ----------------
__global__ void k_bin(const float* __restrict__ coords, const float* __restrict__ edges,
                      int* __restrict__ cellid, int* __restrict__ gcnt) {
  __shared__ float se[3][G+1];
  int tid = threadIdx.x;
  int t = blockIdx.x*256 + tid;
  int b = t >> 15, n = t & (NPTS-1);
  if (tid < 3*(G+1)) se[tid/(G+1)][tid%(G+1)] = edges[b*3*(G+1) + tid];
  __syncthreads();
  const float* cb = coords + (size_t)b*(NPTS*3);
  int c0 = bs16(se[0], cb[n*3+0]);
  int c1 = bs16(se[1], cb[n*3+1]);
  int c2 = bs16(se[2], cb[n*3+2]);
  int cid = b*G3 + (c2*G + c1)*G + c0;
  cellid[t] = cid;
  atomicAdd(&gcnt[cid], 1);
}

// ---------------- deterministic global scan over all 8192 cells ----------------
__global__ void k_alloc(const int* __restrict__ gcnt, int* __restrict__ gstart,
                        int* __restrict__ starts) {
  __shared__ int part[1024];
  int tid = threadIdx.x;
  int v[8]; int s = 0;
#pragma unroll
  for (int i = 0; i < 8; ++i) { v[i] = gcnt[tid*8 + i]; s += v[i]; }
  part[tid] = s;
  __syncthreads();
  for (int off = 1; off < 1024; off <<= 1) {
    int x = part[tid];
    int y = (tid >= off) ? part[tid-off] : 0;
    __syncthreads();
    part[tid] = x + y;
    __syncthreads();
  }
  int base = part[tid] - s;
#pragma unroll
  for (int i = 0; i < 8; ++i) { gstart[tid*8 + i] = base; starts[tid*8 + i] = base; base += v[i]; }
  if (tid == 1023) starts[2*G3] = NQ;
}

// ---------------- scatter: packed float4 + original id, cell-sorted ----------------
__global__ void k_scatter(const float* __restrict__ coords, const int* __restrict__ cellid,
                          int* __restrict__ gstart, float4* __restrict__ csort,
                          int* __restrict__ sortid) {
  int t = blockIdx.x*256 + threadIdx.x;
  int b = t >> 15, n = t & (NPTS-1);
  const float* cb = coords + (size_t)b*(NPTS*3);
  int cid = cellid[t];
  int pos = atomicAdd(&gstart[cid], 1);
  float x = cb[n*3+0], y = cb[n*3+1], z = cb[n*3+2];
  csort[pos] = make_float4(x, y, z, x*x + y*y + z*z);
  sortid[pos] = n;
}

// ---------------- cell-centric KNN: one block per cell, 3x3x3 region in LDS ----------------
__launch_bounds__(256)
__global__ void k_cellknn(const float4* __restrict__ csort, const int* __restrict__ sortid,
                          const int* __restrict__ starts, const float* __restrict__ edges,
                          int* __restrict__ oidx, int* __restrict__ faillist,
                          int* __restrict__ failcnt) {
  __shared__ float4 cand[CAPC];       // 8 KB
  __shared__ int    cid[CAPC];        // 2 KB
  __shared__ float  sdist[4][CAPC];   // 8 KB
  __shared__ int    rs[9], rl[9], pre[10];
  int tid = threadIdx.x, lane = tid & 63, w = tid >> 6;
  int blk = blockIdx.x;
  int b = blk >> 12;                  // G3 = 4096 cells per batch
  int c = blk & (G3-1);
  int cxi = c & 15, cyi = (c >> 4) & 15, czi = c >> 8;
  const int* st = starts + b*G3;
  if (tid < 9) {
    int dz = tid/3 - 1, dy = tid%3 - 1;
    int z = czi + dz, y = cyi + dy;
    if (z < 0 || z > G-1 || y < 0 || y > G-1) { rs[tid] = 0; rl[tid] = 0; }
    else {
      int xa = max(cxi-1, 0), xb = min(cxi+1, G-1);
      int c0 = (z*G + y)*G + xa;
      int s0 = st[c0], e0 = st[c0 + (xb - xa) + 1];
      rs[tid] = s0; rl[tid] = e0 - s0;
    }
  }
  __syncthreads();
  if (tid == 0) {
    int acc = 0;
#pragma unroll
    for (int i = 0; i < 9; ++i) { pre[i] = acc; acc += rl[i]; }
    pre[9] = acc;
  }
  __syncthreads();
  int total = pre[9];
  int hs = st[c], he = st[c+1];
  int nq = he - hs;
  if (nq == 0) return;                           // uniform across block
  bool bad = (total > CAPC) || (total < KK);
  if (!bad) {
    for (int i = tid; i < total; i += 256) {
      int row = 0;
#pragma unroll
      for (int rr = 1; rr < 9; ++rr) row += (i >= pre[rr]);
      int gp = rs[row] + (i - pre[row]);
      cand[i] = csort[gp];
      cid[i]  = sortid[gp];
    }
  }
  __syncthreads();
  int hoff = pre[4] + (hs - rs[4]);              // home cell offset inside cand[]
  // region boundary edge positions (skip sides clipped at the grid border)
  float blo[3], bhi[3]; bool blok[3], bhik[3];
  int cc3[3] = {cxi, cyi, czi};
#pragma unroll
  for (int a = 0; a < 3; ++a) {
    const float* e = edges + (b*3 + a)*(G+1);
    blok[a] = cc3[a] > 0;     blo[a] = blok[a] ? e[cc3[a]-1] : 0.f;
    bhik[a] = cc3[a] < G-1;   bhi[a] = bhik[a] ? e[cc3[a]+2] : 0.f;
  }
  for (int q0 = 0; q0 < nq; q0 += 4) {
    int qi = q0 + w;
    if (qi >= nq) continue;                      // uniform per wave
    int t = hs + qi;                             // query = csort position
    if (bad) {
      if (lane == 0) { int pos = atomicAdd(failcnt, 1); faillist[pos] = t | FB_BAD; }
      continue;
    }
    float4 qv = cand[hoff + qi];
    float qx = qv.x, qy = qv.y, qz = qv.z, qsq = qv.w;
    for (int i = lane; i < total; i += 64) {
      float4 p = cand[i];
      sdist[w][i] = qsq + p.w - 2.f*(qx*p.x + qy*p.y + qz*p.z);  // == reference formula
    }
    int res = 0; float d16v = 0.f;
#pragma unroll
    for (int r = 0; r < KK; ++r) {               // 16 exact extraction rounds
      float lm = 1e30f; int ls2 = 0x7fffffff;
      for (int i = lane; i < total; i += 64) {
        float v = sdist[w][i];
        bool bet = (v < lm) || (v == lm && i < ls2);
        lm = bet ? v : lm; ls2 = bet ? i : ls2;
      }
#pragma unroll
      for (int m = 1; m < 64; m <<= 1) {
        float ov = __shfl_xor(lm, m, 64);
        int   os = __shfl_xor(ls2, m, 64);
        bool bet = (ov < lm) || (ov == lm && os < ls2);
        lm = bet ? ov : lm; ls2 = bet ? os : ls2;
      }
      if (lane == r) res = ls2;
      d16v = lm;                                 // after last round = 16th smallest
      if (lane == 0) sdist[w][ls2] = 1e30f;      // pop winner (wave-coherent LDS)
    }
    // exactness: ball of radius sqrt(d16v) must lie inside the (clipped) region
    float m = 1e30f;
    if (blok[0]) m = fminf(m, qx - blo[0]);
    if (bhik[0]) m = fminf(m, bhi[0] - qx);
    if (blok[1]) m = fminf(m, qy - blo[1]);
    if (bhik[1]) m = fminf(m, bhi[1] - qy);
    if (blok[2]) m = fminf(m, qz - blo[2]);
    if (bhik[2]) m = fminf(m, bhi[2] - qz);
    bool ok = (m > 0.f) && (m*m > d16v + SLOP);
    int qn = cid[hoff + qi];
    size_t row = ((size_t)(b*NPTS + qn))*KK;
    if (ok) {
      if (lane < KK) oidx[row + lane] = cid[res];
    } else {
      // seed the fallback: store the region's exact top-16 as CSORT POSITIONS.
      // cand[] index -> csort position: find row, add offset.
      if (lane < KK) {
        int rr2 = 0;
#pragma unroll
        for (int rr = 1; rr < 9; ++rr) rr2 += (res >= pre[rr]);
        oidx[row + lane] = rs[rr2] + (res - pre[rr2]);
      }
      if (lane == 0) { int pos = atomicAdd(failcnt, 1); faillist[pos] = t; }
    }
  }
}

// ---------------- fallback: seeded resume of the exact shell walk, LDS tables ----------------
__launch_bounds__(256)
__global__ void k_knn_fb(const float4* __restrict__ csort, const int* __restrict__ sortid,
                         const int* __restrict__ starts, const float* __restrict__ edges,
                         const int* __restrict__ faillist, const int* __restrict__ failcnt,
                         int* __restrict__ oidx) {
  __shared__ int lsb[2*(G3+1)];                  // both batches' range tables (32.8 KB)
  int tid = threadIdx.x, lane = tid & 63;
  for (int i = tid; i < G3+1; i += 256) {
    lsb[i] = starts[i];
    lsb[(G3+1) + i] = starts[G3 + i];
  }
  __syncthreads();
  int gw = (blockIdx.x*256 + tid) >> 6;
  int nw = (gridDim.x*256) >> 6;
  int nf = failcnt[0];
  for (int f = gw; f < nf; f += nw) {
    int fv = faillist[f];
    bool seeded = (fv & FB_BAD) == 0;
    int t = fv & (FB_BAD - 1);
    int b = t >> 15;
    const int* st = lsb + b*(G3+1);
    const float* ex = edges + (b*3+0)*(G+1);
    const float* ey = edges + (b*3+1)*(G+1);
    const float* ez = edges + (b*3+2)*(G+1);
    float4 qv = csort[t];
    const float qx = qv.x, qy = qv.y, qz = qv.z, qsq = qv.w;
    const int cx = bs16(ex, qx), cy = bs16(ey, qy), cz = bs16(ez, qz);
    int qn = sortid[t];
    size_t row = ((size_t)(b*NPTS + qn))*KK;
    float dl[KK]; int il[KK];
#pragma unroll
    for (int i = 0; i < KK; ++i) { dl[i] = 1e30f; il[i] = 0; }
    if (seeded && lane < KK) {                   // lane l holds region's l-th NN
      int pos = oidx[row + lane];
      float4 p = csort[pos];
      dl[0] = qsq + p.w - 2.f*(qx*p.x + qy*p.y + qz*p.z);
      il[0] = pos;
    }
    auto prange = [&](int s0, int e0) {
      for (int i = s0 + lane; i < e0; i += 64) {
        float4 p = csort[i];
        float d = qsq + p.w - 2.f*(qx*p.x + qy*p.y + qz*p.z);
        if (d < dl[KK-1]) {
          float cd = d; int ci = i;
#pragma unroll
          for (int i2 = 0; i2 < KK; ++i2) {
            bool sw = cd < dl[i2];
            float td = dl[i2]; int ti = il[i2];
            dl[i2] = sw ? cd : td; il[i2] = sw ? ci : ti;
            cd = sw ? td : cd;    ci = sw ? ti : ci;
          }
        }
      }
    };
    auto prow = [&](int y, int z, int xa, int xb) {
      int c0 = (z*G + y)*G + xa;
      prange(st[c0], st[c0 + (xb - xa) + 1]);
    };
    int r0 = seeded ? 2 : 0;                     // seeds cover shells r<=1 exactly
    for (int r = r0; r <= G; ++r) {
      if (r >= 1) {
        int rm = r - 1;
        if (cx-rm <= 0 && cx+rm >= G-1 && cy-rm <= 0 && cy+rm >= G-1 &&
            cz-rm <= 0 && cz+rm >= G-1) break;
        float v = dl[0];
#pragma unroll
        for (int k2 = 2; k2 <= 64; k2 <<= 1) {
#pragma unroll
          for (int j = k2 >> 1; j > 0; j >>= 1) {
            float o = __shfl_xor(v, j, 64);
            bool keepmin = (((lane & j) == 0) == ((lane & k2) == 0));
            v = keepmin ? fminf(v, o) : fmaxf(v, o);
          }
        }
        float bound = __shfl(v, 15, 64);
        if (bound < 1e29f) {
          float m = 1e30f;
          if (cx-rm > 0)   m = fminf(m, qx - ex[cx-rm]);
          if (cx+rm < G-1) m = fminf(m, ex[cx+rm+1] - qx);
          if (cy-rm > 0)   m = fminf(m, qy - ey[cy-rm]);
          if (cy+rm < G-1) m = fminf(m, ey[cy+rm+1] - qy);
          if (cz-rm > 0)   m = fminf(m, qz - ez[cz-rm]);
          if (cz+rm < G-1) m = fminf(m, ez[cz+rm+1] - qz);
          if (m > 0.f && m*m > bound + SLOP) break;
        }
      }
      int zlo = max(cz-r, 0), zhi = min(cz+r, G-1);
      for (int z = zlo; z <= zhi; ++z) {
        bool zf = (z == cz-r) || (z == cz+r);
        int ylo = max(cy-r, 0), yhi = min(cy+r, G-1);
        for (int y = ylo; y <= yhi; ++y) {
          bool yf = (y == cy-r) || (y == cy+r);
          if (zf || yf) {
            prow(y, z, max(cx-r, 0), min(cx+r, G-1));
          } else {
            if (cx-r >= 0)   prow(y, z, cx-r, cx-r);
            if (cx+r <= G-1) prow(y, z, cx+r, cx+r);
          }
        }
      }
    }
    int res = 0;
#pragma unroll
    for (int r = 0; r < KK; ++r) {
      float v = dl[0]; int l = lane;
#pragma unroll
      for (int m = 1; m < 64; m <<= 1) {
        float ov = __shfl_xor(v, m, 64);
        int   ol = __shfl_xor(l, m, 64);
        bool take = (ov < v) || (ov == v && ol < l);
        v = take ? ov : v;
        l = take ? ol : l;
      }
      int wi = __shfl(il[0], l, 64);
      if (lane == r) res = wi;
      bool win = (lane == l);
#pragma unroll
      for (int i = 0; i < KK-1; ++i) {
        dl[i] = win ? dl[i+1] : dl[i];
        il[i] = win ? il[i+1] : il[i];
      }
      dl[KK-1] = win ? 1e30f : dl[KK-1];
    }
    if (lane < KK) oidx[row + lane] = sortid[res];
  }
}

// ---------------- mlp1 (leaky 0.2) + shortcut BN stats ----------------
__global__ void k_mlp1(const float* __restrict__ features,
                       const float* __restrict__ W1, const float* __restrict__ b1,
                       const float* __restrict__ Wsc, const float* __restrict__ bsc,
                       float* __restrict__ x1, float* __restrict__ stats) {
  __shared__ float sW1[128], sb1[16], sWsc[512], sbsc[64];
  int tid = threadIdx.x;
  if (tid < 128) sW1[tid] = W1[tid];
  if (tid < 16)  sb1[tid] = b1[tid];
  if (tid < 64)  sbsc[tid] = bsc[tid];
  for (int i = tid; i < 512; i += 256) sWsc[i] = Wsc[i];
  __syncthreads();
  int q = blockIdx.x*256 + tid;
  int b = q >> 15, n = q & (NPTS-1);
  float f[8];
#pragma unroll
  for (int c = 0; c < 8; ++c) f[c] = features[((size_t)b*8 + c)*NPTS + n];
#pragma unroll
  for (int co = 0; co < 16; ++co) {
    float a = sb1[co];
#pragma unroll
    for (int c = 0; c < 8; ++c) a += f[c]*sW1[co*8+c];
    x1[(size_t)q*16 + co] = a > 0.f ? a : 0.2f*a;
  }
  int lane = tid & 63;
#pragma unroll
  for (int co = 0; co < 64; ++co) {
    float a = sbsc[co];
#pragma unroll
    for (int c = 0; c < 8; ++c) a += f[c]*sWsc[co*8+c];
    float s = wred64(a), ss = wred64(a*a);
    if (lane == 0) { atomicAdd(&stats[S_SC+co], s); atomicAdd(&stats[S_SC+64+co], ss); }
  }
}

// ---------------- BN stats for BOTH LSE geometric encodings ----------------
__global__ void k_lsestats(const float* __restrict__ coords, const int* __restrict__ idx,
                           const float* __restrict__ Wl1, const float* __restrict__ bl1,
                           const float* __restrict__ Wl2, const float* __restrict__ bl2,
                           float* __restrict__ stats) {
  __shared__ float sW1[160], sb1[16], sW2[160], sb2[16];
  __shared__ float red[4][64];
  int tid = threadIdx.x;
  for (int i = tid; i < 160; i += 256) { sW1[i] = Wl1[i]; sW2[i] = Wl2[i]; }
  if (tid < 16) { sb1[tid] = bl1[tid]; sb2[tid] = bl2[tid]; }
  __syncthreads();
  int t = blockIdx.x*256 + tid;         // (b,n,k) flat
  int q = t >> 4;
  int b = q >> 15, n = q & (NPTS-1);
  const float* cb = coords + (size_t)b*(NPTS*3);
  int j = idx[t];
  float cx = cb[n*3], cy = cb[n*3+1], cz = cb[n*3+2];
  float px = cb[j*3], py = cb[j*3+1], pz = cb[j*3+2];
  float cat[10] = {cx,cy,cz,px,py,pz,cx-px,cy-py,cz-pz,1.f};
  int wave = tid >> 6, lane = tid & 63;
#pragma unroll
  for (int co = 0; co < 16; ++co) {
    float a1 = sb1[co], a2 = sb2[co];
#pragma unroll
    for (int d0 = 0; d0 < 10; ++d0) { a1 += cat[d0]*sW1[co*10+d0]; a2 += cat[d0]*sW2[co*10+d0]; }
    float s1 = wred64(a1), q1 = wred64(a1*a1);
    float s2 = wred64(a2), q2 = wred64(a2*a2);
    if (lane == 0) { red[wave][co]=s1; red[wave][16+co]=q1; red[wave][32+co]=s2; red[wave][48+co]=q2; }
  }
  __syncthreads();
  if (tid < 64) {
    float v = red[0][tid] + red[1][tid] + red[2][tid] + red[3][tid];
    int grp = tid >> 4, c = tid & 15;
    int off = (grp == 0) ? (S_L1 + c) : (grp == 1) ? (S_L1 + 16 + c)
            : (grp == 2) ? (S_L2 + c) : (S_L2 + 16 + c);
    atomicAdd(&stats[off], v);
  }
}

// ---------------- BN finalize ----------------
__global__ void k_bnfin(const float* __restrict__ stats, float* __restrict__ coef,
                        const float* __restrict__ gam, const float* __restrict__ bet,
                        int soff, int coff, int nch, float invc) {
  int c = threadIdx.x;
  if (c < nch) {
    float m = stats[soff + c]*invc;
    float v = stats[soff + nch + c]*invc - m*m;
    float a = gam[c]*rsqrtf(v + EPS);
    coef[coff + c] = a;
    coef[coff + nch + c] = bet[c] - m*a;
  }
}

// ---------------- LSE1 + attentive pooling 1 ----------------
__launch_bounds__(256)
__global__ void k_att1(const float* __restrict__ coords, const int* __restrict__ idx,
                       const float* __restrict__ x1ws,
                       const float* __restrict__ Wl1, const float* __restrict__ bl1,
                       const float* __restrict__ Ws1, const float* __restrict__ Wp1,
                       const float* __restrict__ bp1, const float* __restrict__ coef,
                       float* __restrict__ t2, float* __restrict__ stats) {
  __shared__ float sWl[160], sbl[16];
  __shared__ float sWs[1024];
  __shared__ float sWpT[512], sbp[16];
  __shared__ float lsum[16], lsq[16];
  int tid = threadIdx.x;
  for (int i = tid; i < 160; i += 256) { int c = i/10; sWl[i] = Wl1[i]*coef[C_L1 + c]; }
  if (tid < 16) sbl[tid] = bl1[tid]*coef[C_L1+tid] + coef[C_L1+16+tid];
  for (int i = tid; i < 1024; i += 256) sWs[i] = Ws1[i];
  for (int i = tid; i < 512; i += 256) { int co = i >> 4, cp = i & 15; sWpT[i] = Wp1[cp*32 + co]; }
  if (tid < 16) { sbp[tid] = bp1[tid]; lsum[tid] = 0.f; lsq[tid] = 0.f; }
  __syncthreads();
  int gp = blockIdx.x*16 + (tid >> 4);
  int k  = tid & 15;
  int b = gp >> 15, n = gp & (NPTS-1);
  const float* cb = coords + (size_t)b*(NPTS*3);
  int j = idx[(size_t)gp*KK + k];
  float cx = cb[n*3], cy = cb[n*3+1], cz = cb[n*3+2];
  float px = cb[j*3], py = cb[j*3+1], pz = cb[j*3+2];
  float cat[10] = {cx,cy,cz,px,py,pz,cx-px,cy-py,cz-pz,1.f};
  float x[32];
#pragma unroll
  for (int co = 0; co < 16; ++co) {
    float a = sbl[co];
#pragma unroll
    for (int d0 = 0; d0 < 10; ++d0) a += cat[d0]*sWl[co*10+d0];
    x[co] = a > 0.f ? a : 0.f;
  }
  {
    const float4* xp = (const float4*)(x1ws + (size_t)gp*16);
    float4 u0 = xp[0], u1 = xp[1], u2 = xp[2], u3 = xp[3];
    x[16]=u0.x; x[17]=u0.y; x[18]=u0.z; x[19]=u0.w;
    x[20]=u1.x; x[21]=u1.y; x[22]=u1.z; x[23]=u1.w;
    x[24]=u2.x; x[25]=u2.y; x[26]=u2.z; x[27]=u2.w;
    x[28]=u3.x; x[29]=u3.y; x[30]=u3.z; x[31]=u3.w;
  }
  float tacc = sbp[k];
#pragma unroll
  for (int co = 0; co < 32; ++co) {
    float s = 0.f;
#pragma unroll
    for (int ci = 0; ci < 32; ++ci) s += x[ci]*sWs[co*32+ci];
    float m = s;
#pragma unroll
    for (int msk = 8; msk > 0; msk >>= 1) m = fmaxf(m, __shfl_xor(m, msk, 16));
    float e = __expf(s - m);
    float se = e;
#pragma unroll
    for (int msk = 8; msk > 0; msk >>= 1) se += __shfl_xor(se, msk, 16);
    float w = e/se;
    float fv = w*x[co];
#pragma unroll
    for (int msk = 8; msk > 0; msk >>= 1) fv += __shfl_xor(fv, msk, 16);
    tacc += fv*sWpT[co*16+k];
  }
  t2[(size_t)gp*16 + k] = tacc;
  atomicAdd(&lsum[k], tacc);
  atomicAdd(&lsq[k], tacc*tacc);
  __syncthreads();
  if (tid < 16) { atomicAdd(&stats[S_P1+tid], lsum[tid]); atomicAdd(&stats[S_P1+16+tid], lsq[tid]); }
}

// ---------------- LSE2 + attentive pooling 2 ----------------
__launch_bounds__(256)
__global__ void k_att2(const float* __restrict__ coords, const int* __restrict__ idx,
                       const float* __restrict__ t2ws,
                       const float* __restrict__ Wl2, const float* __restrict__ bl2,
                       const float* __restrict__ Ws2, const float* __restrict__ Wp2,
                       const float* __restrict__ bp2, const float* __restrict__ coef,
                       float* __restrict__ t4, float* __restrict__ stats) {
  __shared__ float sWl[160], sbl[16];
  __shared__ float sWs[1024];
  __shared__ float sWpT[1024], sbp[32];
  __shared__ float sa1[16], sc1[16];
  __shared__ float lsum[32], lsq[32];
  int tid = threadIdx.x;
  for (int i = tid; i < 160; i += 256) { int c = i/10; sWl[i] = Wl2[i]*coef[C_L2 + c]; }
  if (tid < 16) sbl[tid] = bl2[tid]*coef[C_L2+tid] + coef[C_L2+16+tid];
  for (int i = tid; i < 1024; i += 256) {
    sWs[i] = Ws2[i];
    int co = i >> 5, cp = i & 31; sWpT[i] = Wp2[cp*32 + co];
  }
  if (tid < 32) { sbp[tid] = bp2[tid]; lsum[tid]=0.f; lsq[tid]=0.f; }
  if (tid < 16) { sa1[tid] = coef[C_P1+tid]; sc1[tid] = coef[C_P1+16+tid]; }
  __syncthreads();
  int gp = blockIdx.x*16 + (tid >> 4);
  int k  = tid & 15;
  int b = gp >> 15, n = gp & (NPTS-1);
  const float* cb = coords + (size_t)b*(NPTS*3);
  int j = idx[(size_t)gp*KK + k];
  float cx = cb[n*3], cy = cb[n*3+1], cz = cb[n*3+2];
  float px = cb[j*3], py = cb[j*3+1], pz = cb[j*3+2];
  float cat[10] = {cx,cy,cz,px,py,pz,cx-px,cy-py,cz-pz,1.f};
  float x[32];
#pragma unroll
  for (int co = 0; co < 16; ++co) {
    float a = sbl[co];
#pragma unroll
    for (int d0 = 0; d0 < 10; ++d0) a += cat[d0]*sWl[co*10+d0];
    x[co] = a > 0.f ? a : 0.f;
  }
  {
    const float4* xp = (const float4*)(t2ws + (size_t)gp*16);
    float4 u0 = xp[0], u1 = xp[1], u2 = xp[2], u3 = xp[3];
    float xv[16] = {u0.x,u0.y,u0.z,u0.w, u1.x,u1.y,u1.z,u1.w,
                    u2.x,u2.y,u2.z,u2.w, u3.x,u3.y,u3.z,u3.w};
#pragma unroll
    for (int c = 0; c < 16; ++c) {
      float v = xv[c]*sa1[c] + sc1[c];
      x[16+c] = v > 0.f ? v : 0.f;
    }
  }
  float tacc0 = sbp[k], tacc1 = sbp[k+16];
#pragma unroll
  for (int co = 0; co < 32; ++co) {
    float s = 0.f;
#pragma unroll
    for (int ci = 0; ci < 32; ++ci) s += x[ci]*sWs[co*32+ci];
    float m = s;
#pragma unroll
    for (int msk = 8; msk > 0; msk >>= 1) m = fmaxf(m, __shfl_xor(m, msk, 16));
    float e = __expf(s - m);
    float se = e;
#pragma unroll
    for (int msk = 8; msk > 0; msk >>= 1) se += __shfl_xor(se, msk, 16);
    float w = e/se;
    float fv = w*x[co];
#pragma unroll
    for (int msk = 8; msk > 0; msk >>= 1) fv += __shfl_xor(fv, msk, 16);
    tacc0 += fv*sWpT[co*32+k];
    tacc1 += fv*sWpT[co*32+k+16];
  }
  t4[(size_t)gp*32 + k]      = tacc0;
  t4[(size_t)gp*32 + k + 16] = tacc1;
  atomicAdd(&lsum[k], tacc0);      atomicAdd(&lsq[k], tacc0*tacc0);
  atomicAdd(&lsum[k+16], tacc1);   atomicAdd(&lsq[k+16], tacc1*tacc1);
  __syncthreads();
  if (tid < 32) { atomicAdd(&stats[S_P2+tid], lsum[tid]); atomicAdd(&stats[S_P2+32+tid], lsq[tid]); }
}

// ---------------- final: mlp2 + BN'd shortcut + leaky 0.01 ----------------
__global__ void k_final(const float* __restrict__ t4ws, const float* __restrict__ features,
                        const float* __restrict__ W2, const float* __restrict__ b2,
                        const float* __restrict__ Wsc, const float* __restrict__ bsc,
                        const float* __restrict__ coef, float* __restrict__ out) {
  __shared__ float sW2[2048], sb2[64], sWscF[512], sbscF[64], sa[32], scc[32];
  int tid = threadIdx.x;
  for (int i = tid; i < 2048; i += 256) sW2[i] = W2[i];
  if (tid < 64) sb2[tid] = b2[tid];
  for (int i = tid; i < 512; i += 256) { int c2 = i >> 3; sWscF[i] = Wsc[i]*coef[C_SC + c2]; }
  if (tid < 64) sbscF[tid] = bsc[tid]*coef[C_SC+tid] + coef[C_SC+64+tid];
  if (tid < 32) { sa[tid] = coef[C_P2+tid]; scc[tid] = coef[C_P2+32+tid]; }
  __syncthreads();
  int q = blockIdx.x*256 + tid;
  int b = q >> 15, n = q & (NPTS-1);
  float x3[32];
  const float4* tp = (const float4*)(t4ws + (size_t)q*32);
#pragma unroll
  for (int i = 0; i < 8; ++i) {
    float4 u = tp[i];
    float v0 = u.x*sa[4*i+0] + scc[4*i+0];
    float v1 = u.y*sa[4*i+1] + scc[4*i+1];
    float v2 = u.z*sa[4*i+2] + scc[4*i+2];
    float v3 = u.w*sa[4*i+3] + scc[4*i+3];
    x3[4*i+0] = v0 > 0.f ? v0 : 0.f;
    x3[4*i+1] = v1 > 0.f ? v1 : 0.f;
    x3[4*i+2] = v2 > 0.f ? v2 : 0.f;
    x3[4*i+3] = v3 > 0.f ? v3 : 0.f;
  }
  float f[8];
#pragma unroll
  for (int c = 0; c < 8; ++c) f[c] = features[((size_t)b*8+c)*NPTS + n];
  for (int c2 = 0; c2 < 64; ++c2) {
    float acc = sb2[c2];
#pragma unroll
    for (int co = 0; co < 32; ++co) acc += x3[co]*sW2[c2*32+co];
    float sv = sbscF[c2];
#pragma unroll
    for (int c = 0; c < 8; ++c) sv += f[c]*sWscF[c2*8+c];
    float o = acc + sv;
    out[((size_t)b*64 + c2)*NPTS + n] = o > 0.f ? o : 0.01f*o;
  }
}

extern "C" void kernel_launch(void* const* d_in, const int* in_sizes, int n_in,
                              void* d_out, int out_size, void* d_ws, size_t ws_size,
                              hipStream_t stream) {
  const float* coords   = (const float*)d_in[0];
  const float* features = (const float*)d_in[1];
  const float* W1  = (const float*)d_in[2];
  const float* b1  = (const float*)d_in[3];
  const float* Wl1 = (const float*)d_in[4];
  const float* bl1 = (const float*)d_in[5];
  const float* gl1 = (const float*)d_in[6];
  const float* bl1b= (const float*)d_in[7];
  const float* Ws1 = (const float*)d_in[8];
  const float* Wp1 = (const float*)d_in[9];
  const float* bp1 = (const float*)d_in[10];
  const float* gp1 = (const float*)d_in[11];
  const float* bp1b= (const float*)d_in[12];
  const float* Wl2 = (const float*)d_in[13];
  const float* bl2 = (const float*)d_in[14];
  const float* gl2 = (const float*)d_in[15];
  const float* bl2b= (const float*)d_in[16];
  const float* Ws2 = (const float*)d_in[17];
  const float* Wp2 = (const float*)d_in[18];
  const float* bp2 = (const float*)d_in[19];
  const float* gp2 = (const float*)d_in[20];
  const float* bp2b= (const float*)d_in[21];
  const float* W2  = (const float*)d_in[22];
  const float* b2  = (const float*)d_in[23];
  const float* Wsc = (const float*)d_in[24];
  const float* bsc = (const float*)d_in[25];
  const float* gsc = (const float*)d_in[26];
  const float* bscb= (const float*)d_in[27];

  float* wsF  = (float*)d_ws;
  int*   wsI  = (int*)d_ws;
  int*   idxp = wsI;
  float* x1p  = wsF + WS_X1;
  float* t2p  = wsF + WS_T2;
  float* t4p  = wsF + WS_T4;
  float* stat = wsF + WS_STAT;
  float* coef = wsF + WS_COEF;
  int*   gcnt = wsI + WS_GCNT;
  int*   gsta = wsI + WS_GSTART;
  int*   gcel = wsI + WS_CELLID;
  int*   sid  = wsI + WS_SORTID;
  float4* csrt = (float4*)(wsF + WS_CSORT);
  unsigned int* bbox = (unsigned int*)(wsI + WS_BBOX);
  int*   fcnt = wsI + WS_BBOX + 12;       // within bbox's 16-slot region
  int*   flist= wsI + WS_FAIL;            // aliases cellid (dead after scatter)
  int*   hist = wsI + WS_HIST;
  int*   strt = wsI + WS_STARTS;          // aliases hist (dead after k_edges)
  float* edge = wsF + WS_EDGE;
  float* outp = (float*)d_out;

  hipLaunchKernelGGL(k_zero_all, dim3(48), dim3(256), 0, stream, stat, gcnt, hist, bbox, fcnt);
  hipLaunchKernelGGL(k_bbox,    dim3(NQ/256), dim3(256), 0, stream, coords, bbox);
  hipLaunchKernelGGL(k_hist,    dim3(NQ/256), dim3(256), 0, stream, coords, bbox, hist);
  hipLaunchKernelGGL(k_edges,   dim3(6), dim3(256), 0, stream, hist, bbox, edge);
  hipLaunchKernelGGL(k_bin,     dim3(NQ/256), dim3(256), 0, stream, coords, edge, gcel, gcnt);
  hipLaunchKernelGGL(k_alloc,   dim3(1), dim3(1024), 0, stream, gcnt, gsta, strt);
  hipLaunchKernelGGL(k_scatter, dim3(NQ/256), dim3(256), 0, stream, coords, gcel, gsta, csrt, sid);
  hipLaunchKernelGGL(k_cellknn, dim3(2*G3), dim3(256), 0, stream,
                     csrt, sid, strt, edge, idxp, flist, fcnt);
  hipLaunchKernelGGL(k_knn_fb,  dim3(1024), dim3(256), 0, stream,
                     csrt, sid, strt, edge, flist, fcnt, idxp);
  hipLaunchKernelGGL(k_mlp1, dim3(NQ/256), dim3(256), 0, stream,
                     features, W1, b1, Wsc, bsc, x1p, stat);
  hipLaunchKernelGGL(k_lsestats, dim3((NQ*KK)/256), dim3(256), 0, stream,
                     coords, idxp, Wl1, bl1, Wl2, bl2, stat);
  hipLaunchKernelGGL(k_bnfin, dim3(1), dim3(64), 0, stream, stat, coef, gl1, bl1b,
                     S_L1, C_L1, 16, 1.f/(float)((size_t)NQ*KK));
  hipLaunchKernelGGL(k_bnfin, dim3(1), dim3(64), 0, stream, stat, coef, gl2, bl2b,
                     S_L2, C_L2, 16, 1.f/(float)((size_t)NQ*KK));
  hipLaunchKernelGGL(k_bnfin, dim3(1), dim3(64), 0, stream, stat, coef, gsc, bscb,
                     S_SC, C_SC, 64, 1.f/(float)NQ);
  hipLaunchKernelGGL(k_att1, dim3(NQ/16), dim3(256), 0, stream,
                     coords, idxp, x1p, Wl1, bl1, Ws1, Wp1, bp1, coef, t2p, stat);
  hipLaunchKernelGGL(k_bnfin, dim3(1), dim3(64), 0, stream, stat, coef, gp1, bp1b,
                     S_P1, C_P1, 16, 1.f/(float)NQ);
  hipLaunchKernelGGL(k_att2, dim3(NQ/16), dim3(256), 0, stream,
                     coords, idxp, t2p, Wl2, bl2, Ws2, Wp2, bp2, coef, t4p, stat);
  hipLaunchKernelGGL(k_bnfin, dim3(1), dim3(64), 0, stream, stat, coef, gp2, bp2b,
                     S_P2, C_P2, 32, 1.f/(float)NQ);
  hipLaunchKernelGGL(k_final, dim3(NQ/256), dim3(256), 0, stream,
                     t4p, features, W2, b2, Wsc, bsc, coef, outp);
}